// Round 6
// baseline (283.280 us; speedup 1.0000x reference)
//
#include <hip/hip_runtime.h>
#include <math.h>

#define NB 32
#define NN 512
#define ROWC 2048ull

typedef __attribute__((ext_vector_type(8))) short bf16x8;
typedef __attribute__((ext_vector_type(4))) float f32x4;

__device__ __forceinline__ unsigned int fbits(float f) {
  union { float f; unsigned int u; } v; v.f = f; return v.u;
}
__device__ __forceinline__ float bcast(unsigned int u) {
  union { unsigned int u; float f; } v; v.u = u; return v.f;
}
// round-to-nearest-even bf16, returned in low 16 bits
__device__ __forceinline__ unsigned int bf16_rne(float f) {
  unsigned int b = fbits(f);
  return (b + 0x7FFFu + ((b >> 16) & 1u)) >> 16;
}

// Fragment-ordered LDS address for a 128(row)x(32|64)(k) bf16 tile.
// Region (khalf, blk) holds a 16x32 MFMA fragment: lane = (row&15)+16*k8,
// element j = k&7 at +j*2. XOR swizzle on byte[6:4] keeps staged writes
// conflict-free; reads are a bijection within each 1KB region.
// (bank-conflict-free: measured SQ_LDS_BANK_CONFLICT == 0, round 4)
__device__ __forceinline__ int frag_byte(int blk, int lane, int khalf) {
  int base = ((((khalf << 3) + blk) << 6) + lane) << 4;
  int swz = (blk ^ (lane >> 4) ^ (khalf << 2)) & 7;
  return base ^ (swz << 4);
}

// --- Kernel 1: e = px.hx^T (split-bf16 MFMA) + masked row/col softmax stats -
// BK=32, 38KB LDS, <=128 VGPR -> 4 blocks/CU (occupancy was the round-4/5
// bottleneck: 2 blocks/CU, MfmaUtil 5%, all pipes idle).
__global__ __launch_bounds__(256, 4) void gemm_e_stats(
    const float* __restrict__ px, const float* __restrict__ hx,
    const int* __restrict__ p_mask, const int* __restrict__ h_mask,
    float* __restrict__ e,
    float* __restrict__ rpm, float* __restrict__ rps,
    float* __restrict__ cpm, float* __restrict__ cps) {
  __shared__ union {
    struct { char Ah[8192]; char Al[8192]; char Bh[8192]; char Bl[8192]; } s;
    float ep[64][132];
  } u;
  __shared__ int pmk[128], hmk[128];
  __shared__ float st_m[2][128], st_s[2][128], sc_m[2][128], sc_s[2][128];
  const int b = blockIdx.z;
  const float* A = px + (size_t)b * NN * NN;
  const float* B = hx + (size_t)b * NN * NN;
  float* C = e + (size_t)b * NN * NN;
  const int row0 = blockIdx.y * 128, col0 = blockIdx.x * 128;
  const int t = threadIdx.x;
  const int l = t & 63, w = t >> 6;
  const int wr = w >> 1, wc = w & 1;
  const int g = l >> 4, li = l & 15;

  if (t < 128) pmk[t] = p_mask[(size_t)b * NN + row0 + t];
  else hmk[t - 128] = h_mask[(size_t)b * NN + col0 + (t - 128)];

  f32x4 acc[4][4];
#pragma unroll
  for (int i = 0; i < 4; ++i)
#pragma unroll
    for (int j = 0; j < 4; ++j)
#pragma unroll
      for (int r = 0; r < 4; ++r) acc[i][j][r] = 0.f;

  // staging decomposition (BK=32): idx = i*256+t; row = idx>>3; c4 = idx&7
  const int srow = t >> 3, sc4 = t & 7;
  const int sk = sc4 << 2;                    // k offset 0..28
  const int sk8 = sc4 >> 1, sj = (sc4 & 1) << 2;
  // LDS byte for this thread's (row, k) quad at iteration i (row += 32*i)
  float4 fa[4], fb[4];
#pragma unroll
  for (int i = 0; i < 4; ++i) {
    fa[i] = *(const float4*)&A[(size_t)(row0 + srow + 32 * i) * NN + sk];
    fb[i] = *(const float4*)&B[(size_t)(col0 + srow + 32 * i) * NN + sk];
  }

  for (int k0 = 0; k0 < NN; k0 += 32) {
    // ---- convert current fa/fb -> hi/lo bf16, direct LDS writes ----
#pragma unroll
    for (int i = 0; i < 4; ++i) {
      int r = srow + 32 * i;
      int byte = frag_byte(r >> 4, (r & 15) + (sk8 << 4), 0) + (sj << 1);
      float4 f = fa[i];
      unsigned int b0 = fbits(f.x), b1 = fbits(f.y), b2 = fbits(f.z), b3 = fbits(f.w);
      unsigned int h01 = (b0 >> 16) | (b1 & 0xFFFF0000u);
      unsigned int h23 = (b2 >> 16) | (b3 & 0xFFFF0000u);
      float r0 = f.x - bcast(b0 & 0xFFFF0000u);
      float r1 = f.y - bcast(b1 & 0xFFFF0000u);
      float r2 = f.z - bcast(b2 & 0xFFFF0000u);
      float r3 = f.w - bcast(b3 & 0xFFFF0000u);
      unsigned int l01 = (fbits(r0) >> 16) | (fbits(r1) & 0xFFFF0000u);
      unsigned int l23 = (fbits(r2) >> 16) | (fbits(r3) & 0xFFFF0000u);
      *(uint2*)&u.s.Ah[byte] = make_uint2(h01, h23);
      *(uint2*)&u.s.Al[byte] = make_uint2(l01, l23);
      f = fb[i];
      b0 = fbits(f.x); b1 = fbits(f.y); b2 = fbits(f.z); b3 = fbits(f.w);
      h01 = (b0 >> 16) | (b1 & 0xFFFF0000u);
      h23 = (b2 >> 16) | (b3 & 0xFFFF0000u);
      r0 = f.x - bcast(b0 & 0xFFFF0000u);
      r1 = f.y - bcast(b1 & 0xFFFF0000u);
      r2 = f.z - bcast(b2 & 0xFFFF0000u);
      r3 = f.w - bcast(b3 & 0xFFFF0000u);
      l01 = (fbits(r0) >> 16) | (fbits(r1) & 0xFFFF0000u);
      l23 = (fbits(r2) >> 16) | (fbits(r3) & 0xFFFF0000u);
      *(uint2*)&u.s.Bh[byte] = make_uint2(h01, h23);
      *(uint2*)&u.s.Bl[byte] = make_uint2(l01, l23);
    }
    __syncthreads();

    // A-frags resident (32 VGPR)
    bf16x8 ah[4], al[4];
#pragma unroll
    for (int i = 0; i < 4; ++i) {
      int ab = frag_byte(wr * 4 + i, l, 0);
      ah[i] = *(const bf16x8*)&u.s.Ah[ab];
      al[i] = *(const bf16x8*)&u.s.Al[ab];
    }

    // T14: issue next step's global loads now; they fly under the MFMAs
    if (k0 + 32 < NN) {
#pragma unroll
      for (int i = 0; i < 4; ++i) {
        fa[i] = *(const float4*)&A[(size_t)(row0 + srow + 32 * i) * NN + k0 + 32 + sk];
        fb[i] = *(const float4*)&B[(size_t)(col0 + srow + 32 * i) * NN + k0 + 32 + sk];
      }
    }

    // B-frags transient per j (8 VGPR), 48 MFMA per step
#pragma unroll
    for (int j = 0; j < 4; ++j) {
      int bb = frag_byte(wc * 4 + j, l, 0);
      bf16x8 bh = *(const bf16x8*)&u.s.Bh[bb];
      bf16x8 bl = *(const bf16x8*)&u.s.Bl[bb];
#pragma unroll
      for (int i = 0; i < 4; ++i) {
        acc[i][j] = __builtin_amdgcn_mfma_f32_16x16x32_bf16(ah[i], bh, acc[i][j], 0, 0, 0);
        acc[i][j] = __builtin_amdgcn_mfma_f32_16x16x32_bf16(ah[i], bl, acc[i][j], 0, 0, 0);
        acc[i][j] = __builtin_amdgcn_mfma_f32_16x16x32_bf16(al[i], bh, acc[i][j], 0, 0, 0);
      }
    }
    __syncthreads();
  }

  // ---- row stats (softmax over h): max & sum(exp) over this block's 128 cols
#pragma unroll
  for (int i = 0; i < 4; ++i)
#pragma unroll
    for (int r = 0; r < 4; ++r) {
      float v[4];
      float m = -INFINITY;
#pragma unroll
      for (int j = 0; j < 4; ++j) {
        v[j] = hmk[wc * 64 + j * 16 + li] ? -INFINITY : acc[i][j][r];
        m = fmaxf(m, v[j]);
      }
#pragma unroll
      for (int o = 1; o < 16; o <<= 1) m = fmaxf(m, __shfl_xor(m, o));
      float s = 0.f;
#pragma unroll
      for (int j = 0; j < 4; ++j) s += (v[j] == -INFINITY) ? 0.f : __expf(v[j] - m);
#pragma unroll
      for (int o = 1; o < 16; o <<= 1) s += __shfl_xor(s, o);
      if (li == 0) {
        st_m[wc][wr * 64 + i * 16 + g * 4 + r] = m;
        st_s[wc][wr * 64 + i * 16 + g * 4 + r] = s;
      }
    }

  // ---- col stats (softmax over p): max & sum(exp) over this block's 128 rows
#pragma unroll
  for (int j = 0; j < 4; ++j) {
    float v[16];
    float m = -INFINITY;
#pragma unroll
    for (int i = 0; i < 4; ++i)
#pragma unroll
      for (int r = 0; r < 4; ++r) {
        float x = pmk[wr * 64 + i * 16 + g * 4 + r] ? -INFINITY : acc[i][j][r];
        v[i * 4 + r] = x;
        m = fmaxf(m, x);
      }
    m = fmaxf(m, __shfl_xor(m, 16));
    m = fmaxf(m, __shfl_xor(m, 32));
    float s = 0.f;
#pragma unroll
    for (int q = 0; q < 16; ++q) s += (v[q] == -INFINITY) ? 0.f : __expf(v[q] - m);
    s += __shfl_xor(s, 16);
    s += __shfl_xor(s, 32);
    if (g == 0) {
      sc_m[wr][wc * 64 + j * 16 + li] = m;
      sc_s[wr][wc * 64 + j * 16 + li] = s;
    }
  }
  __syncthreads();

  if (t < 128) {
    float m0 = st_m[0][t], m1 = st_m[1][t];
    float s0 = st_s[0][t], s1 = st_s[1][t];
    float m = fmaxf(m0, m1);
    float s = 0.f;
    if (s0 > 0.f) s += s0 * __expf(m0 - m);
    if (s1 > 0.f) s += s1 * __expf(m1 - m);
    rpm[((size_t)b * 4 + blockIdx.x) * NN + row0 + t] = m;
    rps[((size_t)b * 4 + blockIdx.x) * NN + row0 + t] = s;
  } else {
    int c = t - 128;
    float m0 = sc_m[0][c], m1 = sc_m[1][c];
    float s0 = sc_s[0][c], s1 = sc_s[1][c];
    float m = fmaxf(m0, m1);
    float s = 0.f;
    if (s0 > 0.f) s += s0 * __expf(m0 - m);
    if (s1 > 0.f) s += s1 * __expf(m1 - m);
    cpm[((size_t)b * 4 + blockIdx.y) * NN + col0 + c] = m;
    cps[((size_t)b * 4 + blockIdx.y) * NN + col0 + c] = s;
  }

  // ---- E write via LDS bounce -> coalesced float4 stores ----
#pragma unroll
  for (int pass = 0; pass < 2; ++pass) {
    __syncthreads();
    if (wr == pass) {
#pragma unroll
      for (int i = 0; i < 4; ++i)
#pragma unroll
        for (int j = 0; j < 4; ++j)
#pragma unroll
          for (int r = 0; r < 4; ++r)
            u.ep[i * 16 + g * 4 + r][wc * 64 + j * 16 + li] = acc[i][j][r];
    }
    __syncthreads();
#pragma unroll
    for (int i = 0; i < 8; ++i) {
      int idx = i * 256 + t;
      int r = idx >> 5, c4 = idx & 31;
      int grow = row0 + pass * 64 + r;
      float4 v = *(const float4*)&u.ep[r][c4 * 4];
      *(float4*)&C[(size_t)grow * NN + col0 + c4 * 4] = v;
    }
  }
}

// --- Kernel 2: merge 4 partials per row/col (online-softmax merge) ---------
__global__ __launch_bounds__(512) void merge_stats(
    const float* __restrict__ rpm, const float* __restrict__ rps,
    const float* __restrict__ cpm, const float* __restrict__ cps,
    float* __restrict__ rmax, float* __restrict__ rinv,
    float* __restrict__ cmax, float* __restrict__ cinv) {
  const int b = blockIdx.x;
  const int t = threadIdx.x;
  const float* pm = blockIdx.y == 0 ? rpm : cpm;
  const float* ps = blockIdx.y == 0 ? rps : cps;
  float* fm = blockIdx.y == 0 ? rmax : cmax;
  float* fi = blockIdx.y == 0 ? rinv : cinv;
  float mj[4], sj[4];
  float m = -INFINITY;
#pragma unroll
  for (int j = 0; j < 4; ++j) {
    mj[j] = pm[((size_t)b * 4 + j) * NN + t];
    sj[j] = ps[((size_t)b * 4 + j) * NN + t];
    m = fmaxf(m, mj[j]);
  }
  float s = 0.f;
#pragma unroll
  for (int j = 0; j < 4; ++j)
    if (sj[j] > 0.f) s += sj[j] * __expf(mj[j] - m);
  fm[(size_t)b * NN + t] = m;
  fi[(size_t)b * NN + t] = 1.0f / s;
}

// --- Kernel 3: m_p : px_hat = softmax_h(e) @ hx, weights computed on the fly
__global__ __launch_bounds__(256) void gemm_wp(
    const float* __restrict__ E, const float* __restrict__ hxg,
    const float* __restrict__ pxg, const int* __restrict__ h_mask,
    const float* __restrict__ rmax, const float* __restrict__ rinv,
    float* __restrict__ outg) {
  __shared__ union {
    struct { char A[16384]; char B[16384]; } s;
    float ep[64][132];
  } u;
  const int b = blockIdx.z;
  const float* Eb = E + (size_t)b * NN * NN;
  const float* B = hxg + (size_t)b * NN * NN;
  const float* X = pxg + (size_t)b * NN * NN;
  const int* hm = h_mask + (size_t)b * NN;
  const float* rmx = rmax + (size_t)b * NN;
  const float* rin = rinv + (size_t)b * NN;
  float* out = outg + (size_t)b * NN * ROWC;
  const int row0 = blockIdx.y * 128, col0 = blockIdx.x * 128;
  const int t = threadIdx.x;
  const int l = t & 63, w = t >> 6;
  const int wr = w >> 1, wc = w & 1;

  float rmv[8];
#pragma unroll
  for (int i = 0; i < 8; ++i) rmv[i] = rmx[row0 + ((i * 256 + t) >> 4)];

  f32x4 acc[4][4];
#pragma unroll
  for (int i = 0; i < 4; ++i)
#pragma unroll
    for (int j = 0; j < 4; ++j)
#pragma unroll
      for (int r = 0; r < 4; ++r) acc[i][j][r] = 0.f;

  for (int k0 = 0; k0 < NN; k0 += 64) {
    // stage A: w = exp(e - rowmax), masked h -> 0, to bf16 frag order
#pragma unroll
    for (int i = 0; i < 8; ++i) {
      int idx = i * 256 + t;
      int r = idx >> 4, c4 = idx & 15, k = c4 << 2;
      float4 f = *(const float4*)&Eb[(size_t)(row0 + r) * NN + k0 + k];
      int4 m4 = *(const int4*)&hm[k0 + k];
      float w0 = m4.x ? 0.f : __expf(f.x - rmv[i]);
      float w1 = m4.y ? 0.f : __expf(f.y - rmv[i]);
      float w2 = m4.z ? 0.f : __expf(f.z - rmv[i]);
      float w3 = m4.w ? 0.f : __expf(f.w - rmv[i]);
      unsigned int p01 = bf16_rne(w0) | (bf16_rne(w1) << 16);
      unsigned int p23 = bf16_rne(w2) | (bf16_rne(w3) << 16);
      int khalf = k >> 5, k8 = (k >> 3) & 3, j = k & 7;
      int byte = frag_byte(r >> 4, (r & 15) + (k8 << 4), khalf) + (j << 1);
      *(uint2*)&u.s.A[byte] = make_uint2(p01, p23);
    }
    // stage B: hx fp32 [k][n] -> bf16, transposed into frag order (k-pairs)
#pragma unroll
    for (int i = 0; i < 4; ++i) {
      int idx = i * 256 + t;
      int kp = idx >> 5, nq = idx & 31;
      int k = kp << 1, n = nq << 2;
      const float* p0 = &B[(size_t)(k0 + k) * NN + col0 + n];
      float4 f0 = *(const float4*)p0;
      float4 f1 = *(const float4*)(p0 + NN);
      int khalf = k >> 5, k8 = (k >> 3) & 3, j = k & 7;
      float fa0[4] = {f0.x, f0.y, f0.z, f0.w};
      float fa1[4] = {f1.x, f1.y, f1.z, f1.w};
#pragma unroll
      for (int c = 0; c < 4; ++c) {
        unsigned int pk = bf16_rne(fa0[c]) | (bf16_rne(fa1[c]) << 16);
        int nn2 = n + c;
        int byte = frag_byte(nn2 >> 4, (nn2 & 15) + (k8 << 4), khalf) + (j << 1);
        *(unsigned int*)&u.s.B[byte] = pk;
      }
    }
    __syncthreads();
#pragma unroll
    for (int kh = 0; kh < 2; ++kh) {
      bf16x8 av[4], bv[4];
#pragma unroll
      for (int i = 0; i < 4; ++i) {
        av[i] = *(const bf16x8*)&u.s.A[frag_byte(wr * 4 + i, l, kh)];
        bv[i] = *(const bf16x8*)&u.s.B[frag_byte(wc * 4 + i, l, kh)];
      }
#pragma unroll
      for (int i = 0; i < 4; ++i)
#pragma unroll
        for (int j = 0; j < 4; ++j)
          acc[i][j] = __builtin_amdgcn_mfma_f32_16x16x32_bf16(av[i], bv[j], acc[i][j], 0, 0, 0);
    }
    __syncthreads();
  }

  const int g = l >> 4, li = l & 15;
#pragma unroll
  for (int pass = 0; pass < 2; ++pass) {
    if (wr == pass) {
#pragma unroll
      for (int i = 0; i < 4; ++i)
#pragma unroll
        for (int j = 0; j < 4; ++j)
#pragma unroll
          for (int r = 0; r < 4; ++r)
            u.ep[i * 16 + g * 4 + r][wc * 64 + j * 16 + li] = acc[i][j][r];
    }
    __syncthreads();
#pragma unroll
    for (int i = 0; i < 8; ++i) {
      int idx = i * 256 + t;
      int r = idx >> 5, c4 = idx & 31;
      int grow = row0 + pass * 64 + r;
      float ri = rin[grow];
      float4 ph = *(const float4*)&u.ep[r][c4 * 4];
      ph.x *= ri; ph.y *= ri; ph.z *= ri; ph.w *= ri;
      float4 xv = *(const float4*)&X[(size_t)grow * NN + col0 + c4 * 4];
      size_t base = (size_t)grow * ROWC + col0 + c4 * 4;
      *(float4*)&out[base] = xv;
      *(float4*)&out[base + 512] = ph;
      float4 df = {xv.x - ph.x, xv.y - ph.y, xv.z - ph.z, xv.w - ph.w};
      *(float4*)&out[base + 1024] = df;
      float4 pr = {xv.x * ph.x, xv.y * ph.y, xv.z * ph.z, xv.w * ph.w};
      *(float4*)&out[base + 1536] = pr;
    }
    __syncthreads();
  }
}

// --- Kernel 4: m_h : hx_hat = softmax_p(e)^T @ px, weights on the fly ------
__global__ __launch_bounds__(256) void gemm_wh(
    const float* __restrict__ E, const float* __restrict__ pxg,
    const float* __restrict__ hxg, const int* __restrict__ p_mask,
    const float* __restrict__ cmax, const float* __restrict__ cinv,
    float* __restrict__ outg) {
  __shared__ union {
    struct { char A[16384]; char B[16384]; } s;
    float ep[64][132];
  } u;
  const int b = blockIdx.z;
  const float* Eb = E + (size_t)b * NN * NN;
  const float* B = pxg + (size_t)b * NN * NN;
  const float* X = hxg + (size_t)b * NN * NN;
  const int* pmsk = p_mask + (size_t)b * NN;
  const float* cmx = cmax + (size_t)b * NN;
  const float* cin = cinv + (size_t)b * NN;
  float* out = outg + (size_t)b * NN * ROWC;
  const int row0 = blockIdx.y * 128, col0 = blockIdx.x * 128;  // rows = h
  const int t = threadIdx.x;
  const int l = t & 63, w = t >> 6;
  const int wr = w >> 1, wc = w & 1;

  float4 cmv[4];
#pragma unroll
  for (int i = 0; i < 4; ++i) {
    int idx = i * 256 + t;
    int n = (idx & 31) << 2;
    cmv[i] = *(const float4*)&cmx[row0 + n];
  }

  f32x4 acc[4][4];
#pragma unroll
  for (int i = 0; i < 4; ++i)
#pragma unroll
    for (int j = 0; j < 4; ++j)
#pragma unroll
      for (int r = 0; r < 4; ++r) acc[i][j][r] = 0.f;

  for (int k0 = 0; k0 < NN; k0 += 64) {
    // stage A: w[h][p] = exp(e[p][h] - colmax[h]), masked p -> 0 (k-pairs)
#pragma unroll
    for (int i = 0; i < 4; ++i) {
      int idx = i * 256 + t;
      int kp = idx >> 5, nq = idx & 31;
      int k = kp << 1, n = nq << 2;
      const float* p0 = &Eb[(size_t)(k0 + k) * NN + row0 + n];
      float4 f0 = *(const float4*)p0;
      float4 f1 = *(const float4*)(p0 + NN);
      int pm0 = pmsk[k0 + k], pm1 = pmsk[k0 + k + 1];
      float fa0[4] = {f0.x, f0.y, f0.z, f0.w};
      float fa1[4] = {f1.x, f1.y, f1.z, f1.w};
      float cma[4] = {cmv[i].x, cmv[i].y, cmv[i].z, cmv[i].w};
      int khalf = k >> 5, k8 = (k >> 3) & 3, j = k & 7;
#pragma unroll
      for (int c = 0; c < 4; ++c) {
        float w0 = pm0 ? 0.f : __expf(fa0[c] - cma[c]);
        float w1 = pm1 ? 0.f : __expf(fa1[c] - cma[c]);
        unsigned int pk = bf16_rne(w0) | (bf16_rne(w1) << 16);
        int nn2 = n + c;
        int byte = frag_byte(nn2 >> 4, (nn2 & 15) + (k8 << 4), khalf) + (j << 1);
        *(unsigned int*)&u.s.A[byte] = pk;
      }
    }
    // stage B: px fp32 [k][n] -> bf16 frag order (k-pairs)
#pragma unroll
    for (int i = 0; i < 4; ++i) {
      int idx = i * 256 + t;
      int kp = idx >> 5, nq = idx & 31;
      int k = kp << 1, n = nq << 2;
      const float* p0 = &B[(size_t)(k0 + k) * NN + col0 + n];
      float4 f0 = *(const float4*)p0;
      float4 f1 = *(const float4*)(p0 + NN);
      int khalf = k >> 5, k8 = (k >> 3) & 3, j = k & 7;
      float fa0[4] = {f0.x, f0.y, f0.z, f0.w};
      float fa1[4] = {f1.x, f1.y, f1.z, f1.w};
#pragma unroll
      for (int c = 0; c < 4; ++c) {
        unsigned int pk = bf16_rne(fa0[c]) | (bf16_rne(fa1[c]) << 16);
        int nn2 = n + c;
        int byte = frag_byte(nn2 >> 4, (nn2 & 15) + (k8 << 4), khalf) + (j << 1);
        *(unsigned int*)&u.s.B[byte] = pk;
      }
    }
    __syncthreads();
#pragma unroll
    for (int kh = 0; kh < 2; ++kh) {
      bf16x8 av[4], bv[4];
#pragma unroll
      for (int i = 0; i < 4; ++i) {
        av[i] = *(const bf16x8*)&u.s.A[frag_byte(wr * 4 + i, l, kh)];
        bv[i] = *(const bf16x8*)&u.s.B[frag_byte(wc * 4 + i, l, kh)];
      }
#pragma unroll
      for (int i = 0; i < 4; ++i)
#pragma unroll
        for (int j = 0; j < 4; ++j)
          acc[i][j] = __builtin_amdgcn_mfma_f32_16x16x32_bf16(av[i], bv[j], acc[i][j], 0, 0, 0);
    }
    __syncthreads();
  }

  const int g = l >> 4, li = l & 15;
#pragma unroll
  for (int pass = 0; pass < 2; ++pass) {
    if (wr == pass) {
#pragma unroll
      for (int i = 0; i < 4; ++i)
#pragma unroll
        for (int j = 0; j < 4; ++j)
#pragma unroll
          for (int r = 0; r < 4; ++r)
            u.ep[i * 16 + g * 4 + r][wc * 64 + j * 16 + li] = acc[i][j][r];
    }
    __syncthreads();
#pragma unroll
    for (int i = 0; i < 8; ++i) {
      int idx = i * 256 + t;
      int r = idx >> 5, c4 = idx & 31;
      int grow = row0 + pass * 64 + r;  // h
      float ci = cin[grow];
      float4 hh = *(const float4*)&u.ep[r][c4 * 4];
      hh.x *= ci; hh.y *= ci; hh.z *= ci; hh.w *= ci;
      float4 xv = *(const float4*)&X[(size_t)grow * NN + col0 + c4 * 4];
      size_t base = (size_t)grow * ROWC + col0 + c4 * 4;
      *(float4*)&out[base] = xv;
      *(float4*)&out[base + 512] = hh;
      float4 df = {xv.x - hh.x, xv.y - hh.y, xv.z - hh.z, xv.w - hh.w};
      *(float4*)&out[base + 1024] = df;
      float4 pr = {xv.x * hh.x, xv.y * hh.y, xv.z * hh.z, xv.w * hh.w};
      *(float4*)&out[base + 1536] = pr;
    }
    __syncthreads();
  }
}

extern "C" void kernel_launch(void* const* d_in, const int* in_sizes, int n_in,
                              void* d_out, int out_size, void* d_ws, size_t ws_size,
                              hipStream_t stream) {
  const float* px = (const float*)d_in[0];
  const float* hx = (const float*)d_in[1];
  const int* p_mask = (const int*)d_in[2];
  const int* h_mask = (const int*)d_in[3];
  float* out = (float*)d_out;

  float* E = (float*)d_ws;                         // 33.5 MB fp32
  float* rpm = E + (size_t)NB * NN * NN;           // [B][4][NN] partial row max
  float* rps = rpm + (size_t)NB * 4 * NN;
  float* cpm = rps + (size_t)NB * 4 * NN;
  float* cps = cpm + (size_t)NB * 4 * NN;
  float* rmaxv = cps + (size_t)NB * 4 * NN;        // [B][NN] finals
  float* rinvv = rmaxv + (size_t)NB * NN;
  float* cmaxv = rinvv + (size_t)NB * NN;
  float* cinvv = cmaxv + (size_t)NB * NN;

  dim3 blk(256);
  dim3 gg(4, 4, NB);
  gemm_e_stats<<<gg, blk, 0, stream>>>(px, hx, p_mask, h_mask, E, rpm, rps, cpm, cps);
  merge_stats<<<dim3(NB, 2), dim3(512), 0, stream>>>(rpm, rps, cpm, cps,
                                                     rmaxv, rinvv, cmaxv, cinvv);
  gemm_wp<<<gg, blk, 0, stream>>>(E, hx, px, h_mask, rmaxv, rinvv, out);
  gemm_wh<<<gg, blk, 0, stream>>>(E, px, hx, p_mask, cmaxv, cinvv,
                                  out + (size_t)NB * NN * ROWC);
}

// Round 7
// 250.049 us; speedup vs baseline: 1.1329x; 1.1329x over previous
//
#include <hip/hip_runtime.h>
#include <math.h>

#define NB 32
#define NN 512
#define ROWC 2048ull

typedef __attribute__((ext_vector_type(8))) short bf16x8;
typedef __attribute__((ext_vector_type(4))) float f32x4;

__device__ __forceinline__ unsigned int fbits(float f) {
  union { float f; unsigned int u; } v; v.f = f; return v.u;
}
__device__ __forceinline__ float bcast(unsigned int u) {
  union { unsigned int u; float f; } v; v.u = u; return v.f;
}
// round-to-nearest-even bf16, returned in low 16 bits
__device__ __forceinline__ unsigned int bf16_rne(float f) {
  unsigned int b = fbits(f);
  return (b + 0x7FFFu + ((b >> 16) & 1u)) >> 16;
}

// Fragment-ordered LDS address for a 128(row)x64(k) bf16 tile.
// Region (khalf, blk) holds a 16x32 MFMA fragment: lane = (row&15)+16*k8,
// element j = k&7 at +j*2. XOR swizzle on byte[6:4].
// This exact map measured SQ_LDS_BANK_CONFLICT == 0 in round 4.
__device__ __forceinline__ int frag_byte(int blk, int lane, int khalf) {
  int base = ((((khalf << 3) + blk) << 6) + lane) << 4;
  int swz = (blk ^ (lane >> 4) ^ (khalf << 2)) & 7;
  return base ^ (swz << 4);
}

// --- Kernel 1: e = px.hx^T (split-bf16 MFMA) + masked row/col softmax stats -
// 512 threads / 8 waves, wave tile 32x64 -> acc is 32 regs (was 64), resident
// frags 16 (was 64), no prefetch array (was 64). Root cause of rounds 1-6:
// register spill to scratch in the k-loop (round 6: WRITE_SIZE 400MB = scratch).
__global__ __launch_bounds__(512) void gemm_e_stats(
    const float* __restrict__ px, const float* __restrict__ hx,
    const int* __restrict__ p_mask, const int* __restrict__ h_mask,
    float* __restrict__ e,
    float* __restrict__ rpm, float* __restrict__ rps,
    float* __restrict__ cpm, float* __restrict__ cps) {
  __shared__ union {
    struct { char Ah[16384]; char Al[16384]; char Bh[16384]; char Bl[16384]; } s;
    float ep[64][132];
  } u;
  __shared__ int pmk[128], hmk[128];
  __shared__ float st_m[2][128], st_s[2][128], sc_m[4][128], sc_s[4][128];
  const int b = blockIdx.z;
  const float* A = px + (size_t)b * NN * NN;
  const float* B = hx + (size_t)b * NN * NN;
  float* C = e + (size_t)b * NN * NN;
  const int row0 = blockIdx.y * 128, col0 = blockIdx.x * 128;
  const int t = threadIdx.x;
  const int l = t & 63, w = t >> 6;
  const int wr = w >> 1, wc = w & 1;     // wave tile: rows wr*32, cols wc*64
  const int g = l >> 4, li = l & 15;

  if (t < 128) pmk[t] = p_mask[(size_t)b * NN + row0 + t];
  else if (t < 256) hmk[t - 128] = h_mask[(size_t)b * NN + col0 + (t - 128)];

  f32x4 acc[2][4];
#pragma unroll
  for (int i = 0; i < 2; ++i)
#pragma unroll
    for (int j = 0; j < 4; ++j)
#pragma unroll
      for (int r = 0; r < 4; ++r) acc[i][j][r] = 0.f;

  for (int k0 = 0; k0 < NN; k0 += 64) {
    // ---- stage A and B: fp32 -> bf16 hi/lo, inline load/convert/write ----
#pragma unroll
    for (int i = 0; i < 4; ++i) {
      int idx = i * 512 + t;              // 0..2047 float4 units
      int r = idx >> 4, c4 = idx & 15, k = c4 << 2;
      int khalf = k >> 5, k8 = (k >> 3) & 3, j = k & 7;
      int byte = frag_byte(r >> 4, (r & 15) + (k8 << 4), khalf) + (j << 1);
      float4 f = *(const float4*)&A[(size_t)(row0 + r) * NN + k0 + k];
      unsigned int b0 = fbits(f.x), b1 = fbits(f.y), b2 = fbits(f.z), b3 = fbits(f.w);
      unsigned int h01 = (b0 >> 16) | (b1 & 0xFFFF0000u);
      unsigned int h23 = (b2 >> 16) | (b3 & 0xFFFF0000u);
      float r0 = f.x - bcast(b0 & 0xFFFF0000u);
      float r1 = f.y - bcast(b1 & 0xFFFF0000u);
      float r2 = f.z - bcast(b2 & 0xFFFF0000u);
      float r3 = f.w - bcast(b3 & 0xFFFF0000u);
      unsigned int l01 = (fbits(r0) >> 16) | (fbits(r1) & 0xFFFF0000u);
      unsigned int l23 = (fbits(r2) >> 16) | (fbits(r3) & 0xFFFF0000u);
      *(uint2*)&u.s.Ah[byte] = make_uint2(h01, h23);
      *(uint2*)&u.s.Al[byte] = make_uint2(l01, l23);
    }
#pragma unroll
    for (int i = 0; i < 4; ++i) {
      int idx = i * 512 + t;
      int r = idx >> 4, c4 = idx & 15, k = c4 << 2;
      int khalf = k >> 5, k8 = (k >> 3) & 3, j = k & 7;
      int byte = frag_byte(r >> 4, (r & 15) + (k8 << 4), khalf) + (j << 1);
      float4 f = *(const float4*)&B[(size_t)(col0 + r) * NN + k0 + k];
      unsigned int b0 = fbits(f.x), b1 = fbits(f.y), b2 = fbits(f.z), b3 = fbits(f.w);
      unsigned int h01 = (b0 >> 16) | (b1 & 0xFFFF0000u);
      unsigned int h23 = (b2 >> 16) | (b3 & 0xFFFF0000u);
      float r0 = f.x - bcast(b0 & 0xFFFF0000u);
      float r1 = f.y - bcast(b1 & 0xFFFF0000u);
      float r2 = f.z - bcast(b2 & 0xFFFF0000u);
      float r3 = f.w - bcast(b3 & 0xFFFF0000u);
      unsigned int l01 = (fbits(r0) >> 16) | (fbits(r1) & 0xFFFF0000u);
      unsigned int l23 = (fbits(r2) >> 16) | (fbits(r3) & 0xFFFF0000u);
      *(uint2*)&u.s.Bh[byte] = make_uint2(h01, h23);
      *(uint2*)&u.s.Bl[byte] = make_uint2(l01, l23);
    }
    __syncthreads();

#pragma unroll
    for (int kh = 0; kh < 2; ++kh) {
      bf16x8 ah[2], al[2];
#pragma unroll
      for (int i = 0; i < 2; ++i) {
        int ab = frag_byte(wr * 2 + i, l, kh);
        ah[i] = *(const bf16x8*)&u.s.Ah[ab];
        al[i] = *(const bf16x8*)&u.s.Al[ab];
      }
#pragma unroll
      for (int j = 0; j < 4; ++j) {
        int bb = frag_byte(wc * 4 + j, l, kh);
        bf16x8 bh = *(const bf16x8*)&u.s.Bh[bb];
        bf16x8 bl = *(const bf16x8*)&u.s.Bl[bb];
#pragma unroll
        for (int i = 0; i < 2; ++i) {
          acc[i][j] = __builtin_amdgcn_mfma_f32_16x16x32_bf16(ah[i], bh, acc[i][j], 0, 0, 0);
          acc[i][j] = __builtin_amdgcn_mfma_f32_16x16x32_bf16(ah[i], bl, acc[i][j], 0, 0, 0);
          acc[i][j] = __builtin_amdgcn_mfma_f32_16x16x32_bf16(al[i], bh, acc[i][j], 0, 0, 0);
        }
      }
    }
    __syncthreads();
  }

  // ---- row stats (softmax over h): max & sum(exp) over this block's 128 cols
#pragma unroll
  for (int i = 0; i < 2; ++i)
#pragma unroll
    for (int r = 0; r < 4; ++r) {
      float v[4];
      float m = -INFINITY;
#pragma unroll
      for (int j = 0; j < 4; ++j) {
        v[j] = hmk[wc * 64 + j * 16 + li] ? -INFINITY : acc[i][j][r];
        m = fmaxf(m, v[j]);
      }
#pragma unroll
      for (int o = 1; o < 16; o <<= 1) m = fmaxf(m, __shfl_xor(m, o));
      float s = 0.f;
#pragma unroll
      for (int j = 0; j < 4; ++j) s += (v[j] == -INFINITY) ? 0.f : __expf(v[j] - m);
#pragma unroll
      for (int o = 1; o < 16; o <<= 1) s += __shfl_xor(s, o);
      if (li == 0) {
        st_m[wc][wr * 32 + i * 16 + g * 4 + r] = m;
        st_s[wc][wr * 32 + i * 16 + g * 4 + r] = s;
      }
    }

  // ---- col stats (softmax over p): max & sum(exp) over this block's 128 rows
#pragma unroll
  for (int j = 0; j < 4; ++j) {
    float v[8];
    float m = -INFINITY;
#pragma unroll
    for (int i = 0; i < 2; ++i)
#pragma unroll
      for (int r = 0; r < 4; ++r) {
        float x = pmk[wr * 32 + i * 16 + g * 4 + r] ? -INFINITY : acc[i][j][r];
        v[i * 4 + r] = x;
        m = fmaxf(m, x);
      }
    m = fmaxf(m, __shfl_xor(m, 16));
    m = fmaxf(m, __shfl_xor(m, 32));
    float s = 0.f;
#pragma unroll
    for (int q = 0; q < 8; ++q) s += (v[q] == -INFINITY) ? 0.f : __expf(v[q] - m);
    s += __shfl_xor(s, 16);
    s += __shfl_xor(s, 32);
    if (g == 0) {
      sc_m[wr][wc * 64 + j * 16 + li] = m;
      sc_s[wr][wc * 64 + j * 16 + li] = s;
    }
  }
  __syncthreads();

  if (t < 128) {
    float m0 = st_m[0][t], m1 = st_m[1][t];
    float s0 = st_s[0][t], s1 = st_s[1][t];
    float m = fmaxf(m0, m1);
    float s = 0.f;
    if (s0 > 0.f) s += s0 * __expf(m0 - m);
    if (s1 > 0.f) s += s1 * __expf(m1 - m);
    rpm[((size_t)b * 4 + blockIdx.x) * NN + row0 + t] = m;
    rps[((size_t)b * 4 + blockIdx.x) * NN + row0 + t] = s;
  } else if (t < 256) {
    int c = t - 128;
    float m = sc_m[0][c];
#pragma unroll
    for (int q = 1; q < 4; ++q) m = fmaxf(m, sc_m[q][c]);
    float s = 0.f;
#pragma unroll
    for (int q = 0; q < 4; ++q)
      if (sc_s[q][c] > 0.f) s += sc_s[q][c] * __expf(sc_m[q][c] - m);
    cpm[((size_t)b * 4 + blockIdx.y) * NN + col0 + c] = m;
    cps[((size_t)b * 4 + blockIdx.y) * NN + col0 + c] = s;
  }

  // ---- E write via LDS bounce -> coalesced float4 stores ----
#pragma unroll
  for (int pass = 0; pass < 2; ++pass) {
    __syncthreads();
    if ((wr >> 1) == pass) {
#pragma unroll
      for (int i = 0; i < 2; ++i)
#pragma unroll
        for (int j = 0; j < 4; ++j)
#pragma unroll
          for (int r = 0; r < 4; ++r)
            u.ep[(wr & 1) * 32 + i * 16 + g * 4 + r][wc * 64 + j * 16 + li] = acc[i][j][r];
    }
    __syncthreads();
#pragma unroll
    for (int i = 0; i < 4; ++i) {
      int idx = i * 512 + t;
      int r = idx >> 5, c4 = idx & 31;
      int grow = row0 + pass * 64 + r;
      float4 v = *(const float4*)&u.ep[r][c4 * 4];
      *(float4*)&C[(size_t)grow * NN + col0 + c4 * 4] = v;
    }
  }
}

// --- Kernel 2: merge 4 partials per row/col (online-softmax merge) ---------
__global__ __launch_bounds__(512) void merge_stats(
    const float* __restrict__ rpm, const float* __restrict__ rps,
    const float* __restrict__ cpm, const float* __restrict__ cps,
    float* __restrict__ rmax, float* __restrict__ rinv,
    float* __restrict__ cmax, float* __restrict__ cinv) {
  const int b = blockIdx.x;
  const int t = threadIdx.x;
  const float* pm = blockIdx.y == 0 ? rpm : cpm;
  const float* ps = blockIdx.y == 0 ? rps : cps;
  float* fm = blockIdx.y == 0 ? rmax : cmax;
  float* fi = blockIdx.y == 0 ? rinv : cinv;
  float mj[4], sj[4];
  float m = -INFINITY;
#pragma unroll
  for (int j = 0; j < 4; ++j) {
    mj[j] = pm[((size_t)b * 4 + j) * NN + t];
    sj[j] = ps[((size_t)b * 4 + j) * NN + t];
    m = fmaxf(m, mj[j]);
  }
  float s = 0.f;
#pragma unroll
  for (int j = 0; j < 4; ++j)
    if (sj[j] > 0.f) s += sj[j] * __expf(mj[j] - m);
  fm[(size_t)b * NN + t] = m;
  fi[(size_t)b * NN + t] = 1.0f / s;
}

// --- Kernel 3: m_p : px_hat = softmax_h(e) @ hx, weights computed on the fly
__global__ __launch_bounds__(256) void gemm_wp(
    const float* __restrict__ E, const float* __restrict__ hxg,
    const float* __restrict__ pxg, const int* __restrict__ h_mask,
    const float* __restrict__ rmax, const float* __restrict__ rinv,
    float* __restrict__ outg) {
  __shared__ union {
    struct { char A[16384]; char B[16384]; } s;
    float ep[64][132];
  } u;
  const int b = blockIdx.z;
  const float* Eb = E + (size_t)b * NN * NN;
  const float* B = hxg + (size_t)b * NN * NN;
  const float* X = pxg + (size_t)b * NN * NN;
  const int* hm = h_mask + (size_t)b * NN;
  const float* rmx = rmax + (size_t)b * NN;
  const float* rin = rinv + (size_t)b * NN;
  float* out = outg + (size_t)b * NN * ROWC;
  const int row0 = blockIdx.y * 128, col0 = blockIdx.x * 128;
  const int t = threadIdx.x;
  const int l = t & 63, w = t >> 6;
  const int wr = w >> 1, wc = w & 1;

  float rmv[8];
#pragma unroll
  for (int i = 0; i < 8; ++i) rmv[i] = rmx[row0 + ((i * 256 + t) >> 4)];

  f32x4 acc[4][4];
#pragma unroll
  for (int i = 0; i < 4; ++i)
#pragma unroll
    for (int j = 0; j < 4; ++j)
#pragma unroll
      for (int r = 0; r < 4; ++r) acc[i][j][r] = 0.f;

  for (int k0 = 0; k0 < NN; k0 += 64) {
    // stage A: w = exp(e - rowmax), masked h -> 0, to bf16 frag order
#pragma unroll
    for (int i = 0; i < 8; ++i) {
      int idx = i * 256 + t;
      int r = idx >> 4, c4 = idx & 15, k = c4 << 2;
      float4 f = *(const float4*)&Eb[(size_t)(row0 + r) * NN + k0 + k];
      int4 m4 = *(const int4*)&hm[k0 + k];
      float w0 = m4.x ? 0.f : __expf(f.x - rmv[i]);
      float w1 = m4.y ? 0.f : __expf(f.y - rmv[i]);
      float w2 = m4.z ? 0.f : __expf(f.z - rmv[i]);
      float w3 = m4.w ? 0.f : __expf(f.w - rmv[i]);
      unsigned int p01 = bf16_rne(w0) | (bf16_rne(w1) << 16);
      unsigned int p23 = bf16_rne(w2) | (bf16_rne(w3) << 16);
      int khalf = k >> 5, k8 = (k >> 3) & 3, j = k & 7;
      int byte = frag_byte(r >> 4, (r & 15) + (k8 << 4), khalf) + (j << 1);
      *(uint2*)&u.s.A[byte] = make_uint2(p01, p23);
    }
    // stage B: hx fp32 [k][n] -> bf16, transposed into frag order (k-pairs)
#pragma unroll
    for (int i = 0; i < 4; ++i) {
      int idx = i * 256 + t;
      int kp = idx >> 5, nq = idx & 31;
      int k = kp << 1, n = nq << 2;
      const float* p0 = &B[(size_t)(k0 + k) * NN + col0 + n];
      float4 f0 = *(const float4*)p0;
      float4 f1 = *(const float4*)(p0 + NN);
      int khalf = k >> 5, k8 = (k >> 3) & 3, j = k & 7;
      float fa0[4] = {f0.x, f0.y, f0.z, f0.w};
      float fa1[4] = {f1.x, f1.y, f1.z, f1.w};
#pragma unroll
      for (int c = 0; c < 4; ++c) {
        unsigned int pk = bf16_rne(fa0[c]) | (bf16_rne(fa1[c]) << 16);
        int nn2 = n + c;
        int byte = frag_byte(nn2 >> 4, (nn2 & 15) + (k8 << 4), khalf) + (j << 1);
        *(unsigned int*)&u.s.B[byte] = pk;
      }
    }
    __syncthreads();
#pragma unroll
    for (int kh = 0; kh < 2; ++kh) {
      bf16x8 av[4], bv[4];
#pragma unroll
      for (int i = 0; i < 4; ++i) {
        av[i] = *(const bf16x8*)&u.s.A[frag_byte(wr * 4 + i, l, kh)];
        bv[i] = *(const bf16x8*)&u.s.B[frag_byte(wc * 4 + i, l, kh)];
      }
#pragma unroll
      for (int i = 0; i < 4; ++i)
#pragma unroll
        for (int j = 0; j < 4; ++j)
          acc[i][j] = __builtin_amdgcn_mfma_f32_16x16x32_bf16(av[i], bv[j], acc[i][j], 0, 0, 0);
    }
    __syncthreads();
  }

  const int g = l >> 4, li = l & 15;
#pragma unroll
  for (int pass = 0; pass < 2; ++pass) {
    if (wr == pass) {
#pragma unroll
      for (int i = 0; i < 4; ++i)
#pragma unroll
        for (int j = 0; j < 4; ++j)
#pragma unroll
          for (int r = 0; r < 4; ++r)
            u.ep[i * 16 + g * 4 + r][wc * 64 + j * 16 + li] = acc[i][j][r];
    }
    __syncthreads();
#pragma unroll
    for (int i = 0; i < 8; ++i) {
      int idx = i * 256 + t;
      int r = idx >> 5, c4 = idx & 31;
      int grow = row0 + pass * 64 + r;
      float ri = rin[grow];
      float4 ph = *(const float4*)&u.ep[r][c4 * 4];
      ph.x *= ri; ph.y *= ri; ph.z *= ri; ph.w *= ri;
      float4 xv = *(const float4*)&X[(size_t)grow * NN + col0 + c4 * 4];
      size_t base = (size_t)grow * ROWC + col0 + c4 * 4;
      *(float4*)&out[base] = xv;
      *(float4*)&out[base + 512] = ph;
      float4 df = {xv.x - ph.x, xv.y - ph.y, xv.z - ph.z, xv.w - ph.w};
      *(float4*)&out[base + 1024] = df;
      float4 pr = {xv.x * ph.x, xv.y * ph.y, xv.z * ph.z, xv.w * ph.w};
      *(float4*)&out[base + 1536] = pr;
    }
    __syncthreads();
  }
}

// --- Kernel 4: m_h : hx_hat = softmax_p(e)^T @ px, weights on the fly ------
__global__ __launch_bounds__(256) void gemm_wh(
    const float* __restrict__ E, const float* __restrict__ pxg,
    const float* __restrict__ hxg, const int* __restrict__ p_mask,
    const float* __restrict__ cmax, const float* __restrict__ cinv,
    float* __restrict__ outg) {
  __shared__ union {
    struct { char A[16384]; char B[16384]; } s;
    float ep[64][132];
  } u;
  const int b = blockIdx.z;
  const float* Eb = E + (size_t)b * NN * NN;
  const float* B = pxg + (size_t)b * NN * NN;
  const float* X = hxg + (size_t)b * NN * NN;
  const int* pmsk = p_mask + (size_t)b * NN;
  const float* cmx = cmax + (size_t)b * NN;
  const float* cin = cinv + (size_t)b * NN;
  float* out = outg + (size_t)b * NN * ROWC;
  const int row0 = blockIdx.y * 128, col0 = blockIdx.x * 128;  // rows = h
  const int t = threadIdx.x;
  const int l = t & 63, w = t >> 6;
  const int wr = w >> 1, wc = w & 1;

  float4 cmv[4];
#pragma unroll
  for (int i = 0; i < 4; ++i) {
    int idx = i * 256 + t;
    int n = (idx & 31) << 2;
    cmv[i] = *(const float4*)&cmx[row0 + n];
  }

  f32x4 acc[4][4];
#pragma unroll
  for (int i = 0; i < 4; ++i)
#pragma unroll
    for (int j = 0; j < 4; ++j)
#pragma unroll
      for (int r = 0; r < 4; ++r) acc[i][j][r] = 0.f;

  for (int k0 = 0; k0 < NN; k0 += 64) {
    // stage A: w[h][p] = exp(e[p][h] - colmax[h]), masked p -> 0 (k-pairs)
#pragma unroll
    for (int i = 0; i < 4; ++i) {
      int idx = i * 256 + t;
      int kp = idx >> 5, nq = idx & 31;
      int k = kp << 1, n = nq << 2;
      const float* p0 = &Eb[(size_t)(k0 + k) * NN + row0 + n];
      float4 f0 = *(const float4*)p0;
      float4 f1 = *(const float4*)(p0 + NN);
      int pm0 = pmsk[k0 + k], pm1 = pmsk[k0 + k + 1];
      float fa0[4] = {f0.x, f0.y, f0.z, f0.w};
      float fa1[4] = {f1.x, f1.y, f1.z, f1.w};
      float cma[4] = {cmv[i].x, cmv[i].y, cmv[i].z, cmv[i].w};
      int khalf = k >> 5, k8 = (k >> 3) & 3, j = k & 7;
#pragma unroll
      for (int c = 0; c < 4; ++c) {
        float w0 = pm0 ? 0.f : __expf(fa0[c] - cma[c]);
        float w1 = pm1 ? 0.f : __expf(fa1[c] - cma[c]);
        unsigned int pk = bf16_rne(w0) | (bf16_rne(w1) << 16);
        int nn2 = n + c;
        int byte = frag_byte(nn2 >> 4, (nn2 & 15) + (k8 << 4), khalf) + (j << 1);
        *(unsigned int*)&u.s.A[byte] = pk;
      }
    }
    // stage B: px fp32 [k][n] -> bf16 frag order (k-pairs)
#pragma unroll
    for (int i = 0; i < 4; ++i) {
      int idx = i * 256 + t;
      int kp = idx >> 5, nq = idx & 31;
      int k = kp << 1, n = nq << 2;
      const float* p0 = &B[(size_t)(k0 + k) * NN + col0 + n];
      float4 f0 = *(const float4*)p0;
      float4 f1 = *(const float4*)(p0 + NN);
      int khalf = k >> 5, k8 = (k >> 3) & 3, j = k & 7;
      float fa0[4] = {f0.x, f0.y, f0.z, f0.w};
      float fa1[4] = {f1.x, f1.y, f1.z, f1.w};
#pragma unroll
      for (int c = 0; c < 4; ++c) {
        unsigned int pk = bf16_rne(fa0[c]) | (bf16_rne(fa1[c]) << 16);
        int nn2 = n + c;
        int byte = frag_byte(nn2 >> 4, (nn2 & 15) + (k8 << 4), khalf) + (j << 1);
        *(unsigned int*)&u.s.B[byte] = pk;
      }
    }
    __syncthreads();
#pragma unroll
    for (int kh = 0; kh < 2; ++kh) {
      bf16x8 av[4], bv[4];
#pragma unroll
      for (int i = 0; i < 4; ++i) {
        av[i] = *(const bf16x8*)&u.s.A[frag_byte(wr * 4 + i, l, kh)];
        bv[i] = *(const bf16x8*)&u.s.B[frag_byte(wc * 4 + i, l, kh)];
      }
#pragma unroll
      for (int i = 0; i < 4; ++i)
#pragma unroll
        for (int j = 0; j < 4; ++j)
          acc[i][j] = __builtin_amdgcn_mfma_f32_16x16x32_bf16(av[i], bv[j], acc[i][j], 0, 0, 0);
    }
    __syncthreads();
  }

  const int g = l >> 4, li = l & 15;
#pragma unroll
  for (int pass = 0; pass < 2; ++pass) {
    if (wr == pass) {
#pragma unroll
      for (int i = 0; i < 4; ++i)
#pragma unroll
        for (int j = 0; j < 4; ++j)
#pragma unroll
          for (int r = 0; r < 4; ++r)
            u.ep[i * 16 + g * 4 + r][wc * 64 + j * 16 + li] = acc[i][j][r];
    }
    __syncthreads();
#pragma unroll
    for (int i = 0; i < 8; ++i) {
      int idx = i * 256 + t;
      int r = idx >> 5, c4 = idx & 31;
      int grow = row0 + pass * 64 + r;  // h
      float ci = cin[grow];
      float4 hh = *(const float4*)&u.ep[r][c4 * 4];
      hh.x *= ci; hh.y *= ci; hh.z *= ci; hh.w *= ci;
      float4 xv = *(const float4*)&X[(size_t)grow * NN + col0 + c4 * 4];
      size_t base = (size_t)grow * ROWC + col0 + c4 * 4;
      *(float4*)&out[base] = xv;
      *(float4*)&out[base + 512] = hh;
      float4 df = {xv.x - hh.x, xv.y - hh.y, xv.z - hh.z, xv.w - hh.w};
      *(float4*)&out[base + 1024] = df;
      float4 pr = {xv.x * hh.x, xv.y * hh.y, xv.z * hh.z, xv.w * hh.w};
      *(float4*)&out[base + 1536] = pr;
    }
    __syncthreads();
  }
}

extern "C" void kernel_launch(void* const* d_in, const int* in_sizes, int n_in,
                              void* d_out, int out_size, void* d_ws, size_t ws_size,
                              hipStream_t stream) {
  const float* px = (const float*)d_in[0];
  const float* hx = (const float*)d_in[1];
  const int* p_mask = (const int*)d_in[2];
  const int* h_mask = (const int*)d_in[3];
  float* out = (float*)d_out;

  float* E = (float*)d_ws;                         // 33.5 MB fp32
  float* rpm = E + (size_t)NB * NN * NN;           // [B][4][NN] partial row max
  float* rps = rpm + (size_t)NB * 4 * NN;
  float* cpm = rps + (size_t)NB * 4 * NN;
  float* cps = cpm + (size_t)NB * 4 * NN;
  float* rmaxv = cps + (size_t)NB * 4 * NN;        // [B][NN] finals
  float* rinvv = rmaxv + (size_t)NB * NN;
  float* cmaxv = rinvv + (size_t)NB * NN;
  float* cinvv = cmaxv + (size_t)NB * NN;

  dim3 gg(4, 4, NB);
  gemm_e_stats<<<gg, dim3(512), 0, stream>>>(px, hx, p_mask, h_mask, E, rpm, rps, cpm, cps);
  merge_stats<<<dim3(NB, 2), dim3(512), 0, stream>>>(rpm, rps, cpm, cps,
                                                     rmaxv, rinvv, cmaxv, cinvv);
  gemm_wp<<<gg, dim3(256), 0, stream>>>(E, hx, px, h_mask, rmaxv, rinvv, out);
  gemm_wh<<<gg, dim3(256), 0, stream>>>(E, px, hx, p_mask, cmaxv, cinvv,
                                        out + (size_t)NB * NN * ROWC);
}

// Round 8
// 208.901 us; speedup vs baseline: 1.3561x; 1.1970x over previous
//
#include <hip/hip_runtime.h>
#include <math.h>

#define NB 32
#define NN 512
#define ROWC 2048ull

typedef __attribute__((ext_vector_type(8))) short bf16x8;
typedef __attribute__((ext_vector_type(4))) float f32x4;

__device__ __forceinline__ unsigned int fbits(float f) {
  union { float f; unsigned int u; } v; v.f = f; return v.u;
}
__device__ __forceinline__ float bcast(unsigned int u) {
  union { unsigned int u; float f; } v; v.u = u; return v.f;
}
// round-to-nearest-even bf16, returned in low 16 bits
__device__ __forceinline__ unsigned int bf16_rne(float f) {
  unsigned int b = fbits(f);
  return (b + 0x7FFFu + ((b >> 16) & 1u)) >> 16;
}

// Fragment-ordered LDS address used by gemm_wp / gemm_wh (unchanged).
__device__ __forceinline__ int frag_byte(int blk, int lane, int khalf) {
  int base = ((((khalf << 3) + blk) << 6) + lane) << 4;
  int swz = (blk ^ (lane >> 4) ^ (khalf << 2)) & 7;
  return base ^ (swz << 4);
}

// gemm_e v4 LDS layout: bf16 [128 rows][64 k] row-major (128 B/row),
// 16B units XOR-swizzled within the row: unit' = unit ^ (row&7).
// Staging writes (8B halves) hit all 32 banks exactly once per 16-thread row
// group; ds_read_b128 fragment reads are 2-way (free).
__device__ __forceinline__ int ebyte(int row, int unit) {
  return row * 128 + ((unit ^ (row & 7)) << 4);
}

// --- Kernel 1: e = px.hx^T (split-bf16 MFMA) + masked row/col softmax stats -
__global__ __launch_bounds__(512) void gemm_e_stats(
    const float* __restrict__ px, const float* __restrict__ hx,
    const int* __restrict__ p_mask, const int* __restrict__ h_mask,
    float* __restrict__ e,
    float* __restrict__ rpm, float* __restrict__ rps,
    float* __restrict__ cpm, float* __restrict__ cps) {
  __shared__ union {
    struct { char Ah[16384]; char Al[16384]; char Bh[16384]; char Bl[16384]; } s;
    struct { float st_m[2][128]; float st_s[2][128];
             float sc_m[4][128]; float sc_s[4][128]; } x;
    float ep[64][132];
  } u;
  const int b = blockIdx.z;
  const float* A = px + (size_t)b * NN * NN;
  const float* B = hx + (size_t)b * NN * NN;
  float* C = e + (size_t)b * NN * NN;
  const int row0 = blockIdx.y * 128, col0 = blockIdx.x * 128;
  const int t = threadIdx.x;
  const int l = t & 63, w = t >> 6;
  const int wr = w >> 1, wc = w & 1;     // wave tile: rows wr*32, cols wc*64
  const int g = l >> 4, li = l & 15;

  f32x4 acc[2][4];
#pragma unroll
  for (int i = 0; i < 2; ++i)
#pragma unroll
    for (int j = 0; j < 4; ++j)
#pragma unroll
      for (int r = 0; r < 4; ++r) acc[i][j][r] = 0.f;

  // staging decomposition: thread handles rows r_i = i*32 + (t>>4), u = t&15
  const int sr = t >> 4, su = t & 15;
  const int sbyte0 = ((su >> 1) << 4);   // unit pre-swizzle = su>>1, half su&1
  const int shalf = (su & 1) * 8;

  float4 fa[4], fb[4];
#pragma unroll
  for (int i = 0; i < 4; ++i) {
    fa[i] = *(const float4*)&A[(size_t)(row0 + sr + 32 * i) * NN + su * 4];
    fb[i] = *(const float4*)&B[(size_t)(col0 + sr + 32 * i) * NN + su * 4];
  }

  for (int k0 = 0; k0 < NN; k0 += 64) {
    // ---- convert current fa/fb -> bf16 hi/lo, conflict-free ds_write_b64 ---
#pragma unroll
    for (int i = 0; i < 4; ++i) {
      int r = sr + 32 * i;
      int byte = r * 128 + ((((su >> 1) ^ (r & 7)) << 4)) + shalf;
      float4 f = fa[i];
      unsigned int b0 = fbits(f.x), b1 = fbits(f.y), b2 = fbits(f.z), b3 = fbits(f.w);
      unsigned int h01 = (b0 >> 16) | (b1 & 0xFFFF0000u);
      unsigned int h23 = (b2 >> 16) | (b3 & 0xFFFF0000u);
      float r0 = f.x - bcast(b0 & 0xFFFF0000u);
      float r1 = f.y - bcast(b1 & 0xFFFF0000u);
      float r2 = f.z - bcast(b2 & 0xFFFF0000u);
      float r3 = f.w - bcast(b3 & 0xFFFF0000u);
      unsigned int l01 = (fbits(r0) >> 16) | (fbits(r1) & 0xFFFF0000u);
      unsigned int l23 = (fbits(r2) >> 16) | (fbits(r3) & 0xFFFF0000u);
      *(uint2*)&u.s.Ah[byte] = make_uint2(h01, h23);
      *(uint2*)&u.s.Al[byte] = make_uint2(l01, l23);
      f = fb[i];
      b0 = fbits(f.x); b1 = fbits(f.y); b2 = fbits(f.z); b3 = fbits(f.w);
      h01 = (b0 >> 16) | (b1 & 0xFFFF0000u);
      h23 = (b2 >> 16) | (b3 & 0xFFFF0000u);
      r0 = f.x - bcast(b0 & 0xFFFF0000u);
      r1 = f.y - bcast(b1 & 0xFFFF0000u);
      r2 = f.z - bcast(b2 & 0xFFFF0000u);
      r3 = f.w - bcast(b3 & 0xFFFF0000u);
      l01 = (fbits(r0) >> 16) | (fbits(r1) & 0xFFFF0000u);
      l23 = (fbits(r2) >> 16) | (fbits(r3) & 0xFFFF0000u);
      *(uint2*)&u.s.Bh[byte] = make_uint2(h01, h23);
      *(uint2*)&u.s.Bl[byte] = make_uint2(l01, l23);
    }
    __syncthreads();

    // prefetch next k-step's tiles into registers (flies under the MFMAs)
    if (k0 + 64 < NN) {
#pragma unroll
      for (int i = 0; i < 4; ++i) {
        fa[i] = *(const float4*)&A[(size_t)(row0 + sr + 32 * i) * NN + k0 + 64 + su * 4];
        fb[i] = *(const float4*)&B[(size_t)(col0 + sr + 32 * i) * NN + k0 + 64 + su * 4];
      }
    }

#pragma unroll
    for (int kh = 0; kh < 2; ++kh) {
      bf16x8 ah[2], al[2];
#pragma unroll
      for (int i = 0; i < 2; ++i) {
        int row = wr * 32 + i * 16 + li;
        int ab = ebyte(row, kh * 4 + g);
        ah[i] = *(const bf16x8*)&u.s.Ah[ab];
        al[i] = *(const bf16x8*)&u.s.Al[ab];
      }
#pragma unroll
      for (int j = 0; j < 4; ++j) {
        int col = wc * 64 + j * 16 + li;
        int bb = ebyte(col, kh * 4 + g);
        bf16x8 bh = *(const bf16x8*)&u.s.Bh[bb];
        bf16x8 bl = *(const bf16x8*)&u.s.Bl[bb];
#pragma unroll
        for (int i = 0; i < 2; ++i) {
          acc[i][j] = __builtin_amdgcn_mfma_f32_16x16x32_bf16(ah[i], bh, acc[i][j], 0, 0, 0);
          acc[i][j] = __builtin_amdgcn_mfma_f32_16x16x32_bf16(ah[i], bl, acc[i][j], 0, 0, 0);
          acc[i][j] = __builtin_amdgcn_mfma_f32_16x16x32_bf16(al[i], bh, acc[i][j], 0, 0, 0);
        }
      }
    }
    __syncthreads();
  }

  // ---- masks into registers (L2-hot; 2KB per block) ----
  int hmr[4], pmr[2][4];
#pragma unroll
  for (int j = 0; j < 4; ++j)
    hmr[j] = h_mask[(size_t)b * NN + col0 + wc * 64 + j * 16 + li];
#pragma unroll
  for (int i = 0; i < 2; ++i)
#pragma unroll
    for (int r = 0; r < 4; ++r)
      pmr[i][r] = p_mask[(size_t)b * NN + row0 + wr * 32 + i * 16 + g * 4 + r];

  // ---- row stats (softmax over h): max & sum(exp) over this block's 128 cols
#pragma unroll
  for (int i = 0; i < 2; ++i)
#pragma unroll
    for (int r = 0; r < 4; ++r) {
      float v[4];
      float m = -INFINITY;
#pragma unroll
      for (int j = 0; j < 4; ++j) {
        v[j] = hmr[j] ? -INFINITY : acc[i][j][r];
        m = fmaxf(m, v[j]);
      }
#pragma unroll
      for (int o = 1; o < 16; o <<= 1) m = fmaxf(m, __shfl_xor(m, o));
      float s = 0.f;
#pragma unroll
      for (int j = 0; j < 4; ++j) s += (v[j] == -INFINITY) ? 0.f : __expf(v[j] - m);
#pragma unroll
      for (int o = 1; o < 16; o <<= 1) s += __shfl_xor(s, o);
      if (li == 0) {
        u.x.st_m[wc][wr * 32 + i * 16 + g * 4 + r] = m;
        u.x.st_s[wc][wr * 32 + i * 16 + g * 4 + r] = s;
      }
    }

  // ---- col stats (softmax over p): max & sum(exp) over this block's 128 rows
#pragma unroll
  for (int j = 0; j < 4; ++j) {
    float v[8];
    float m = -INFINITY;
#pragma unroll
    for (int i = 0; i < 2; ++i)
#pragma unroll
      for (int r = 0; r < 4; ++r) {
        float x = pmr[i][r] ? -INFINITY : acc[i][j][r];
        v[i * 4 + r] = x;
        m = fmaxf(m, x);
      }
    m = fmaxf(m, __shfl_xor(m, 16));
    m = fmaxf(m, __shfl_xor(m, 32));
    float s = 0.f;
#pragma unroll
    for (int q = 0; q < 8; ++q) s += (v[q] == -INFINITY) ? 0.f : __expf(v[q] - m);
    s += __shfl_xor(s, 16);
    s += __shfl_xor(s, 32);
    if (g == 0) {
      u.x.sc_m[wr][wc * 64 + j * 16 + li] = m;
      u.x.sc_s[wr][wc * 64 + j * 16 + li] = s;
    }
  }
  __syncthreads();

  if (t < 128) {
    float m0 = u.x.st_m[0][t], m1 = u.x.st_m[1][t];
    float s0 = u.x.st_s[0][t], s1 = u.x.st_s[1][t];
    float m = fmaxf(m0, m1);
    float s = 0.f;
    if (s0 > 0.f) s += s0 * __expf(m0 - m);
    if (s1 > 0.f) s += s1 * __expf(m1 - m);
    rpm[((size_t)b * 4 + blockIdx.x) * NN + row0 + t] = m;
    rps[((size_t)b * 4 + blockIdx.x) * NN + row0 + t] = s;
  } else if (t < 256) {
    int c = t - 128;
    float m = u.x.sc_m[0][c];
#pragma unroll
    for (int q = 1; q < 4; ++q) m = fmaxf(m, u.x.sc_m[q][c]);
    float s = 0.f;
#pragma unroll
    for (int q = 0; q < 4; ++q)
      if (u.x.sc_s[q][c] > 0.f) s += u.x.sc_s[q][c] * __expf(u.x.sc_m[q][c] - m);
    cpm[((size_t)b * 4 + blockIdx.y) * NN + col0 + c] = m;
    cps[((size_t)b * 4 + blockIdx.y) * NN + col0 + c] = s;
  }

  // ---- E write via LDS bounce -> coalesced float4 stores ----
#pragma unroll
  for (int pass = 0; pass < 2; ++pass) {
    __syncthreads();
    if ((wr >> 1) == pass) {
#pragma unroll
      for (int i = 0; i < 2; ++i)
#pragma unroll
        for (int j = 0; j < 4; ++j)
#pragma unroll
          for (int r = 0; r < 4; ++r)
            u.ep[(wr & 1) * 32 + i * 16 + g * 4 + r][wc * 64 + j * 16 + li] = acc[i][j][r];
    }
    __syncthreads();
#pragma unroll
    for (int i = 0; i < 4; ++i) {
      int idx = i * 512 + t;
      int r = idx >> 5, c4 = idx & 31;
      int grow = row0 + pass * 64 + r;
      float4 v = *(const float4*)&u.ep[r][c4 * 4];
      *(float4*)&C[(size_t)grow * NN + col0 + c4 * 4] = v;
    }
  }
}

// --- Kernel 2: merge 4 partials per row/col (online-softmax merge) ---------
__global__ __launch_bounds__(512) void merge_stats(
    const float* __restrict__ rpm, const float* __restrict__ rps,
    const float* __restrict__ cpm, const float* __restrict__ cps,
    float* __restrict__ rmax, float* __restrict__ rinv,
    float* __restrict__ cmax, float* __restrict__ cinv) {
  const int b = blockIdx.x;
  const int t = threadIdx.x;
  const float* pm = blockIdx.y == 0 ? rpm : cpm;
  const float* ps = blockIdx.y == 0 ? rps : cps;
  float* fm = blockIdx.y == 0 ? rmax : cmax;
  float* fi = blockIdx.y == 0 ? rinv : cinv;
  float mj[4], sj[4];
  float m = -INFINITY;
#pragma unroll
  for (int j = 0; j < 4; ++j) {
    mj[j] = pm[((size_t)b * 4 + j) * NN + t];
    sj[j] = ps[((size_t)b * 4 + j) * NN + t];
    m = fmaxf(m, mj[j]);
  }
  float s = 0.f;
#pragma unroll
  for (int j = 0; j < 4; ++j)
    if (sj[j] > 0.f) s += sj[j] * __expf(mj[j] - m);
  fm[(size_t)b * NN + t] = m;
  fi[(size_t)b * NN + t] = 1.0f / s;
}

// --- Kernel 3: m_p : px_hat = softmax_h(e) @ hx, weights computed on the fly
__global__ __launch_bounds__(256) void gemm_wp(
    const float* __restrict__ E, const float* __restrict__ hxg,
    const float* __restrict__ pxg, const int* __restrict__ h_mask,
    const float* __restrict__ rmax, const float* __restrict__ rinv,
    float* __restrict__ outg) {
  __shared__ union {
    struct { char A[16384]; char B[16384]; } s;
    float ep[64][132];
  } u;
  const int b = blockIdx.z;
  const float* Eb = E + (size_t)b * NN * NN;
  const float* B = hxg + (size_t)b * NN * NN;
  const float* X = pxg + (size_t)b * NN * NN;
  const int* hm = h_mask + (size_t)b * NN;
  const float* rmx = rmax + (size_t)b * NN;
  const float* rin = rinv + (size_t)b * NN;
  float* out = outg + (size_t)b * NN * ROWC;
  const int row0 = blockIdx.y * 128, col0 = blockIdx.x * 128;
  const int t = threadIdx.x;
  const int l = t & 63, w = t >> 6;
  const int wr = w >> 1, wc = w & 1;

  float rmv[8];
#pragma unroll
  for (int i = 0; i < 8; ++i) rmv[i] = rmx[row0 + ((i * 256 + t) >> 4)];

  f32x4 acc[4][4];
#pragma unroll
  for (int i = 0; i < 4; ++i)
#pragma unroll
    for (int j = 0; j < 4; ++j)
#pragma unroll
      for (int r = 0; r < 4; ++r) acc[i][j][r] = 0.f;

  for (int k0 = 0; k0 < NN; k0 += 64) {
    // stage A: w = exp(e - rowmax), masked h -> 0, to bf16 frag order
#pragma unroll
    for (int i = 0; i < 8; ++i) {
      int idx = i * 256 + t;
      int r = idx >> 4, c4 = idx & 15, k = c4 << 2;
      float4 f = *(const float4*)&Eb[(size_t)(row0 + r) * NN + k0 + k];
      int4 m4 = *(const int4*)&hm[k0 + k];
      float w0 = m4.x ? 0.f : __expf(f.x - rmv[i]);
      float w1 = m4.y ? 0.f : __expf(f.y - rmv[i]);
      float w2 = m4.z ? 0.f : __expf(f.z - rmv[i]);
      float w3 = m4.w ? 0.f : __expf(f.w - rmv[i]);
      unsigned int p01 = bf16_rne(w0) | (bf16_rne(w1) << 16);
      unsigned int p23 = bf16_rne(w2) | (bf16_rne(w3) << 16);
      int khalf = k >> 5, k8 = (k >> 3) & 3, j = k & 7;
      int byte = frag_byte(r >> 4, (r & 15) + (k8 << 4), khalf) + (j << 1);
      *(uint2*)&u.s.A[byte] = make_uint2(p01, p23);
    }
    // stage B: hx fp32 [k][n] -> bf16, transposed into frag order (k-pairs)
#pragma unroll
    for (int i = 0; i < 4; ++i) {
      int idx = i * 256 + t;
      int kp = idx >> 5, nq = idx & 31;
      int k = kp << 1, n = nq << 2;
      const float* p0 = &B[(size_t)(k0 + k) * NN + col0 + n];
      float4 f0 = *(const float4*)p0;
      float4 f1 = *(const float4*)(p0 + NN);
      int khalf = k >> 5, k8 = (k >> 3) & 3, j = k & 7;
      float fa0[4] = {f0.x, f0.y, f0.z, f0.w};
      float fa1[4] = {f1.x, f1.y, f1.z, f1.w};
#pragma unroll
      for (int c = 0; c < 4; ++c) {
        unsigned int pk = bf16_rne(fa0[c]) | (bf16_rne(fa1[c]) << 16);
        int nn2 = n + c;
        int byte = frag_byte(nn2 >> 4, (nn2 & 15) + (k8 << 4), khalf) + (j << 1);
        *(unsigned int*)&u.s.B[byte] = pk;
      }
    }
    __syncthreads();
#pragma unroll
    for (int kh = 0; kh < 2; ++kh) {
      bf16x8 av[4], bv[4];
#pragma unroll
      for (int i = 0; i < 4; ++i) {
        av[i] = *(const bf16x8*)&u.s.A[frag_byte(wr * 4 + i, l, kh)];
        bv[i] = *(const bf16x8*)&u.s.B[frag_byte(wc * 4 + i, l, kh)];
      }
#pragma unroll
      for (int i = 0; i < 4; ++i)
#pragma unroll
        for (int j = 0; j < 4; ++j)
          acc[i][j] = __builtin_amdgcn_mfma_f32_16x16x32_bf16(av[i], bv[j], acc[i][j], 0, 0, 0);
    }
    __syncthreads();
  }

  const int g = l >> 4, li = l & 15;
#pragma unroll
  for (int pass = 0; pass < 2; ++pass) {
    if (wr == pass) {
#pragma unroll
      for (int i = 0; i < 4; ++i)
#pragma unroll
        for (int j = 0; j < 4; ++j)
#pragma unroll
          for (int r = 0; r < 4; ++r)
            u.ep[i * 16 + g * 4 + r][wc * 64 + j * 16 + li] = acc[i][j][r];
    }
    __syncthreads();
#pragma unroll
    for (int i = 0; i < 8; ++i) {
      int idx = i * 256 + t;
      int r = idx >> 5, c4 = idx & 31;
      int grow = row0 + pass * 64 + r;
      float ri = rin[grow];
      float4 ph = *(const float4*)&u.ep[r][c4 * 4];
      ph.x *= ri; ph.y *= ri; ph.z *= ri; ph.w *= ri;
      float4 xv = *(const float4*)&X[(size_t)grow * NN + col0 + c4 * 4];
      size_t base = (size_t)grow * ROWC + col0 + c4 * 4;
      *(float4*)&out[base] = xv;
      *(float4*)&out[base + 512] = ph;
      float4 df = {xv.x - ph.x, xv.y - ph.y, xv.z - ph.z, xv.w - ph.w};
      *(float4*)&out[base + 1024] = df;
      float4 pr = {xv.x * ph.x, xv.y * ph.y, xv.z * ph.z, xv.w * ph.w};
      *(float4*)&out[base + 1536] = pr;
    }
    __syncthreads();
  }
}

// --- Kernel 4: m_h : hx_hat = softmax_p(e)^T @ px, weights on the fly ------
__global__ __launch_bounds__(256) void gemm_wh(
    const float* __restrict__ E, const float* __restrict__ pxg,
    const float* __restrict__ hxg, const int* __restrict__ p_mask,
    const float* __restrict__ cmax, const float* __restrict__ cinv,
    float* __restrict__ outg) {
  __shared__ union {
    struct { char A[16384]; char B[16384]; } s;
    float ep[64][132];
  } u;
  const int b = blockIdx.z;
  const float* Eb = E + (size_t)b * NN * NN;
  const float* B = pxg + (size_t)b * NN * NN;
  const float* X = hxg + (size_t)b * NN * NN;
  const int* pmsk = p_mask + (size_t)b * NN;
  const float* cmx = cmax + (size_t)b * NN;
  const float* cin = cinv + (size_t)b * NN;
  float* out = outg + (size_t)b * NN * ROWC;
  const int row0 = blockIdx.y * 128, col0 = blockIdx.x * 128;  // rows = h
  const int t = threadIdx.x;
  const int l = t & 63, w = t >> 6;
  const int wr = w >> 1, wc = w & 1;

  float4 cmv[4];
#pragma unroll
  for (int i = 0; i < 4; ++i) {
    int idx = i * 256 + t;
    int n = (idx & 31) << 2;
    cmv[i] = *(const float4*)&cmx[row0 + n];
  }

  f32x4 acc[4][4];
#pragma unroll
  for (int i = 0; i < 4; ++i)
#pragma unroll
    for (int j = 0; j < 4; ++j)
#pragma unroll
      for (int r = 0; r < 4; ++r) acc[i][j][r] = 0.f;

  for (int k0 = 0; k0 < NN; k0 += 64) {
    // stage A: w[h][p] = exp(e[p][h] - colmax[h]), masked p -> 0 (k-pairs)
#pragma unroll
    for (int i = 0; i < 4; ++i) {
      int idx = i * 256 + t;
      int kp = idx >> 5, nq = idx & 31;
      int k = kp << 1, n = nq << 2;
      const float* p0 = &Eb[(size_t)(k0 + k) * NN + row0 + n];
      float4 f0 = *(const float4*)p0;
      float4 f1 = *(const float4*)(p0 + NN);
      int pm0 = pmsk[k0 + k], pm1 = pmsk[k0 + k + 1];
      float fa0[4] = {f0.x, f0.y, f0.z, f0.w};
      float fa1[4] = {f1.x, f1.y, f1.z, f1.w};
      float cma[4] = {cmv[i].x, cmv[i].y, cmv[i].z, cmv[i].w};
      int khalf = k >> 5, k8 = (k >> 3) & 3, j = k & 7;
#pragma unroll
      for (int c = 0; c < 4; ++c) {
        float w0 = pm0 ? 0.f : __expf(fa0[c] - cma[c]);
        float w1 = pm1 ? 0.f : __expf(fa1[c] - cma[c]);
        unsigned int pk = bf16_rne(w0) | (bf16_rne(w1) << 16);
        int nn2 = n + c;
        int byte = frag_byte(nn2 >> 4, (nn2 & 15) + (k8 << 4), khalf) + (j << 1);
        *(unsigned int*)&u.s.A[byte] = pk;
      }
    }
    // stage B: px fp32 [k][n] -> bf16 frag order (k-pairs)
#pragma unroll
    for (int i = 0; i < 4; ++i) {
      int idx = i * 256 + t;
      int kp = idx >> 5, nq = idx & 31;
      int k = kp << 1, n = nq << 2;
      const float* p0 = &B[(size_t)(k0 + k) * NN + col0 + n];
      float4 f0 = *(const float4*)p0;
      float4 f1 = *(const float4*)(p0 + NN);
      int khalf = k >> 5, k8 = (k >> 3) & 3, j = k & 7;
      float fa0[4] = {f0.x, f0.y, f0.z, f0.w};
      float fa1[4] = {f1.x, f1.y, f1.z, f1.w};
#pragma unroll
      for (int c = 0; c < 4; ++c) {
        unsigned int pk = bf16_rne(fa0[c]) | (bf16_rne(fa1[c]) << 16);
        int nn2 = n + c;
        int byte = frag_byte(nn2 >> 4, (nn2 & 15) + (k8 << 4), khalf) + (j << 1);
        *(unsigned int*)&u.s.B[byte] = pk;
      }
    }
    __syncthreads();
#pragma unroll
    for (int kh = 0; kh < 2; ++kh) {
      bf16x8 av[4], bv[4];
#pragma unroll
      for (int i = 0; i < 4; ++i) {
        av[i] = *(const bf16x8*)&u.s.A[frag_byte(wr * 4 + i, l, kh)];
        bv[i] = *(const bf16x8*)&u.s.B[frag_byte(wc * 4 + i, l, kh)];
      }
#pragma unroll
      for (int i = 0; i < 4; ++i)
#pragma unroll
        for (int j = 0; j < 4; ++j)
          acc[i][j] = __builtin_amdgcn_mfma_f32_16x16x32_bf16(av[i], bv[j], acc[i][j], 0, 0, 0);
    }
    __syncthreads();
  }

  const int g = l >> 4, li = l & 15;
#pragma unroll
  for (int pass = 0; pass < 2; ++pass) {
    if (wr == pass) {
#pragma unroll
      for (int i = 0; i < 4; ++i)
#pragma unroll
        for (int j = 0; j < 4; ++j)
#pragma unroll
          for (int r = 0; r < 4; ++r)
            u.ep[i * 16 + g * 4 + r][wc * 64 + j * 16 + li] = acc[i][j][r];
    }
    __syncthreads();
#pragma unroll
    for (int i = 0; i < 8; ++i) {
      int idx = i * 256 + t;
      int r = idx >> 5, c4 = idx & 31;
      int grow = row0 + pass * 64 + r;  // h
      float ci = cin[grow];
      float4 hh = *(const float4*)&u.ep[r][c4 * 4];
      hh.x *= ci; hh.y *= ci; hh.z *= ci; hh.w *= ci;
      float4 xv = *(const float4*)&X[(size_t)grow * NN + col0 + c4 * 4];
      size_t base = (size_t)grow * ROWC + col0 + c4 * 4;
      *(float4*)&out[base] = xv;
      *(float4*)&out[base + 512] = hh;
      float4 df = {xv.x - hh.x, xv.y - hh.y, xv.z - hh.z, xv.w - hh.w};
      *(float4*)&out[base + 1024] = df;
      float4 pr = {xv.x * hh.x, xv.y * hh.y, xv.z * hh.z, xv.w * hh.w};
      *(float4*)&out[base + 1536] = pr;
    }
    __syncthreads();
  }
}

extern "C" void kernel_launch(void* const* d_in, const int* in_sizes, int n_in,
                              void* d_out, int out_size, void* d_ws, size_t ws_size,
                              hipStream_t stream) {
  const float* px = (const float*)d_in[0];
  const float* hx = (const float*)d_in[1];
  const int* p_mask = (const int*)d_in[2];
  const int* h_mask = (const int*)d_in[3];
  float* out = (float*)d_out;

  float* E = (float*)d_ws;                         // 33.5 MB fp32
  float* rpm = E + (size_t)NB * NN * NN;           // [B][4][NN] partial row max
  float* rps = rpm + (size_t)NB * 4 * NN;
  float* cpm = rps + (size_t)NB * 4 * NN;
  float* cps = cpm + (size_t)NB * 4 * NN;
  float* rmaxv = cps + (size_t)NB * 4 * NN;        // [B][NN] finals
  float* rinvv = rmaxv + (size_t)NB * NN;
  float* cmaxv = rinvv + (size_t)NB * NN;
  float* cinvv = cmaxv + (size_t)NB * NN;

  dim3 gg(4, 4, NB);
  gemm_e_stats<<<gg, dim3(512), 0, stream>>>(px, hx, p_mask, h_mask, E, rpm, rps, cpm, cps);
  merge_stats<<<dim3(NB, 2), dim3(512), 0, stream>>>(rpm, rps, cpm, cps,
                                                     rmaxv, rinvv, cmaxv, cinvv);
  gemm_wp<<<gg, dim3(256), 0, stream>>>(E, hx, px, h_mask, rmaxv, rinvv, out);
  gemm_wh<<<gg, dim3(256), 0, stream>>>(E, px, hx, p_mask, cmaxv, cinvv,
                                        out + (size_t)NB * NN * ROWC);
}

// Round 9
// 208.153 us; speedup vs baseline: 1.3609x; 1.0036x over previous
//
#include <hip/hip_runtime.h>
#include <math.h>

#define NB 32
#define NN 512
#define ROWC 2048ull

typedef __attribute__((ext_vector_type(8))) short bf16x8;
typedef __attribute__((ext_vector_type(4))) float f32x4;

__device__ __forceinline__ unsigned int fbits(float f) {
  union { float f; unsigned int u; } v; v.f = f; return v.u;
}
__device__ __forceinline__ float bcast(unsigned int u) {
  union { unsigned int u; float f; } v; v.u = u; return v.f;
}
// round-to-nearest-even bf16, returned in low 16 bits
__device__ __forceinline__ unsigned int bf16_rne(float f) {
  unsigned int b = fbits(f);
  return (b + 0x7FFFu + ((b >> 16) & 1u)) >> 16;
}

// split one fp32x4 into truncated-hi bf16x4 (8B) and exact-residual-lo bf16x4
__device__ __forceinline__ void cvt_hilo(float4 f, uint2& hi, uint2& lo) {
  unsigned int b0 = fbits(f.x), b1 = fbits(f.y), b2 = fbits(f.z), b3 = fbits(f.w);
  hi.x = (b0 >> 16) | (b1 & 0xFFFF0000u);
  hi.y = (b2 >> 16) | (b3 & 0xFFFF0000u);
  float r0 = f.x - bcast(b0 & 0xFFFF0000u);
  float r1 = f.y - bcast(b1 & 0xFFFF0000u);
  float r2 = f.z - bcast(b2 & 0xFFFF0000u);
  float r3 = f.w - bcast(b3 & 0xFFFF0000u);
  lo.x = (fbits(r0) >> 16) | (fbits(r1) & 0xFFFF0000u);
  lo.y = (fbits(r2) >> 16) | (fbits(r3) & 0xFFFF0000u);
}

// Fragment-ordered LDS address used by gemm_wp / gemm_wh (unchanged, proven).
__device__ __forceinline__ int frag_byte(int blk, int lane, int khalf) {
  int base = ((((khalf << 3) + blk) << 6) + lane) << 4;
  int swz = (blk ^ (lane >> 4) ^ (khalf << 2)) & 7;
  return base ^ (swz << 4);
}

// gemm_e BK=32 LDS layout: bf16 [128 rows][32 k], 64 B/row, 16B units
// XOR-swizzled within the row (unit' = unit ^ (row&3)): staging ds_write_b64
// lands at uniform 4-deep bank pairs (minimum), frag ds_read_b128 <=4-way.
__device__ __forceinline__ int ebyte32(int row, int unit) {
  return row * 64 + (((unit ^ (row & 3)) << 4));
}

// --- Kernel 1: e = px.hx^T (split-bf16 MFMA) + masked row/col softmax stats -
// LDS total 33.8 KB (= gemm_wp's size, the kernel measured at its memory
// floor) -> 3-4 blocks/CU. Rounds 4-8 root cause: LDS >64KB forced 1 block/CU
// (OccupancyPercent 11.6/22.6% == exactly one 4/8-wave block) -> zero TLP.
__global__ __launch_bounds__(512) void gemm_e_stats(
    const float* __restrict__ px, const float* __restrict__ hx,
    const int* __restrict__ p_mask, const int* __restrict__ h_mask,
    float* __restrict__ e,
    float* __restrict__ rpm, float* __restrict__ rps,
    float* __restrict__ cpm, float* __restrict__ cps) {
  __shared__ union {
    struct { char Ah[8192]; char Al[8192]; char Bh[8192]; char Bl[8192]; } s;
    struct { float st_m[2][128]; float st_s[2][128];
             float sc_m[4][128]; float sc_s[4][128]; } x;
    float ep[64][132];
  } u;
  const int b = blockIdx.z;
  const float* A = px + (size_t)b * NN * NN;
  const float* B = hx + (size_t)b * NN * NN;
  float* C = e + (size_t)b * NN * NN;
  const int row0 = blockIdx.y * 128, col0 = blockIdx.x * 128;
  const int t = threadIdx.x;
  const int l = t & 63, w = t >> 6;
  const int wr = w >> 1, wc = w & 1;     // wave tile: rows wr*32, cols wc*64
  const int g = l >> 4, li = l & 15;

  f32x4 acc[2][4];
#pragma unroll
  for (int i = 0; i < 2; ++i)
#pragma unroll
    for (int j = 0; j < 4; ++j)
#pragma unroll
      for (int r = 0; r < 4; ++r) acc[i][j][r] = 0.f;

  // staging: thread covers (row = 64*i + (t>>3), fq = t&7), k = fq*4
  const int sr = t >> 3, fq = t & 7;
  const int sbyte = sr * 64 + (((fq >> 1) ^ (sr & 3)) << 4) + (fq & 1) * 8;

  float4 fa[2], fb[2];
#pragma unroll
  for (int i = 0; i < 2; ++i) {
    fa[i] = *(const float4*)&A[(size_t)(row0 + sr + 64 * i) * NN + fq * 4];
    fb[i] = *(const float4*)&B[(size_t)(col0 + sr + 64 * i) * NN + fq * 4];
  }

  for (int k0 = 0; k0 < NN; k0 += 32) {
    // ---- convert current fa/fb -> bf16 hi/lo, uniform-depth ds_write_b64 ---
#pragma unroll
    for (int i = 0; i < 2; ++i) {
      int byte = sbyte + i * 4096;       // row += 64 -> +64*64 bytes
      uint2 hi, lo;
      cvt_hilo(fa[i], hi, lo);
      *(uint2*)&u.s.Ah[byte] = hi;
      *(uint2*)&u.s.Al[byte] = lo;
      cvt_hilo(fb[i], hi, lo);
      *(uint2*)&u.s.Bh[byte] = hi;
      *(uint2*)&u.s.Bl[byte] = lo;
    }
    __syncthreads();

    // prefetch next k-step's tiles into registers (flies under the MFMAs)
    if (k0 + 32 < NN) {
#pragma unroll
      for (int i = 0; i < 2; ++i) {
        fa[i] = *(const float4*)&A[(size_t)(row0 + sr + 64 * i) * NN + k0 + 32 + fq * 4];
        fb[i] = *(const float4*)&B[(size_t)(col0 + sr + 64 * i) * NN + k0 + 32 + fq * 4];
      }
    }

    bf16x8 ah[2], al[2];
#pragma unroll
    for (int i = 0; i < 2; ++i) {
      int ab = ebyte32(wr * 32 + i * 16 + li, g);
      ah[i] = *(const bf16x8*)&u.s.Ah[ab];
      al[i] = *(const bf16x8*)&u.s.Al[ab];
    }
#pragma unroll
    for (int j = 0; j < 4; ++j) {
      int bb = ebyte32(wc * 64 + j * 16 + li, g);
      bf16x8 bh = *(const bf16x8*)&u.s.Bh[bb];
      bf16x8 bl = *(const bf16x8*)&u.s.Bl[bb];
#pragma unroll
      for (int i = 0; i < 2; ++i) {
        acc[i][j] = __builtin_amdgcn_mfma_f32_16x16x32_bf16(ah[i], bh, acc[i][j], 0, 0, 0);
        acc[i][j] = __builtin_amdgcn_mfma_f32_16x16x32_bf16(ah[i], bl, acc[i][j], 0, 0, 0);
        acc[i][j] = __builtin_amdgcn_mfma_f32_16x16x32_bf16(al[i], bh, acc[i][j], 0, 0, 0);
      }
    }
    __syncthreads();
  }

  // ---- masks into registers (L2-hot; 2KB per block) ----
  int hmr[4], pmr[2][4];
#pragma unroll
  for (int j = 0; j < 4; ++j)
    hmr[j] = h_mask[(size_t)b * NN + col0 + wc * 64 + j * 16 + li];
#pragma unroll
  for (int i = 0; i < 2; ++i)
#pragma unroll
    for (int r = 0; r < 4; ++r)
      pmr[i][r] = p_mask[(size_t)b * NN + row0 + wr * 32 + i * 16 + g * 4 + r];

  // ---- row stats (softmax over h): max & sum(exp) over this block's 128 cols
#pragma unroll
  for (int i = 0; i < 2; ++i)
#pragma unroll
    for (int r = 0; r < 4; ++r) {
      float v[4];
      float m = -INFINITY;
#pragma unroll
      for (int j = 0; j < 4; ++j) {
        v[j] = hmr[j] ? -INFINITY : acc[i][j][r];
        m = fmaxf(m, v[j]);
      }
#pragma unroll
      for (int o = 1; o < 16; o <<= 1) m = fmaxf(m, __shfl_xor(m, o));
      float s = 0.f;
#pragma unroll
      for (int j = 0; j < 4; ++j) s += (v[j] == -INFINITY) ? 0.f : __expf(v[j] - m);
#pragma unroll
      for (int o = 1; o < 16; o <<= 1) s += __shfl_xor(s, o);
      if (li == 0) {
        u.x.st_m[wc][wr * 32 + i * 16 + g * 4 + r] = m;
        u.x.st_s[wc][wr * 32 + i * 16 + g * 4 + r] = s;
      }
    }

  // ---- col stats (softmax over p): max & sum(exp) over this block's 128 rows
#pragma unroll
  for (int j = 0; j < 4; ++j) {
    float v[8];
    float m = -INFINITY;
#pragma unroll
    for (int i = 0; i < 2; ++i)
#pragma unroll
      for (int r = 0; r < 4; ++r) {
        float x = pmr[i][r] ? -INFINITY : acc[i][j][r];
        v[i * 4 + r] = x;
        m = fmaxf(m, x);
      }
    m = fmaxf(m, __shfl_xor(m, 16));
    m = fmaxf(m, __shfl_xor(m, 32));
    float s = 0.f;
#pragma unroll
    for (int q = 0; q < 8; ++q) s += (v[q] == -INFINITY) ? 0.f : __expf(v[q] - m);
    s += __shfl_xor(s, 16);
    s += __shfl_xor(s, 32);
    if (g == 0) {
      u.x.sc_m[wr][wc * 64 + j * 16 + li] = m;
      u.x.sc_s[wr][wc * 64 + j * 16 + li] = s;
    }
  }
  __syncthreads();

  if (t < 128) {
    float m0 = u.x.st_m[0][t], m1 = u.x.st_m[1][t];
    float s0 = u.x.st_s[0][t], s1 = u.x.st_s[1][t];
    float m = fmaxf(m0, m1);
    float s = 0.f;
    if (s0 > 0.f) s += s0 * __expf(m0 - m);
    if (s1 > 0.f) s += s1 * __expf(m1 - m);
    rpm[((size_t)b * 4 + blockIdx.x) * NN + row0 + t] = m;
    rps[((size_t)b * 4 + blockIdx.x) * NN + row0 + t] = s;
  } else if (t < 256) {
    int c = t - 128;
    float m = u.x.sc_m[0][c];
#pragma unroll
    for (int q = 1; q < 4; ++q) m = fmaxf(m, u.x.sc_m[q][c]);
    float s = 0.f;
#pragma unroll
    for (int q = 0; q < 4; ++q)
      if (u.x.sc_s[q][c] > 0.f) s += u.x.sc_s[q][c] * __expf(u.x.sc_m[q][c] - m);
    cpm[((size_t)b * 4 + blockIdx.y) * NN + col0 + c] = m;
    cps[((size_t)b * 4 + blockIdx.y) * NN + col0 + c] = s;
  }

  // ---- E write via LDS bounce -> coalesced float4 stores ----
#pragma unroll
  for (int pass = 0; pass < 2; ++pass) {
    __syncthreads();
    if ((wr >> 1) == pass) {
#pragma unroll
      for (int i = 0; i < 2; ++i)
#pragma unroll
        for (int j = 0; j < 4; ++j)
#pragma unroll
          for (int r = 0; r < 4; ++r)
            u.ep[(wr & 1) * 32 + i * 16 + g * 4 + r][wc * 64 + j * 16 + li] = acc[i][j][r];
    }
    __syncthreads();
#pragma unroll
    for (int i = 0; i < 4; ++i) {
      int idx = i * 512 + t;
      int r = idx >> 5, c4 = idx & 31;
      int grow = row0 + pass * 64 + r;
      float4 v = *(const float4*)&u.ep[r][c4 * 4];
      *(float4*)&C[(size_t)grow * NN + col0 + c4 * 4] = v;
    }
  }
}

// --- Kernel 2: merge 4 partials per row/col (online-softmax merge) ---------
__global__ __launch_bounds__(512) void merge_stats(
    const float* __restrict__ rpm, const float* __restrict__ rps,
    const float* __restrict__ cpm, const float* __restrict__ cps,
    float* __restrict__ rmax, float* __restrict__ rinv,
    float* __restrict__ cmax, float* __restrict__ cinv) {
  const int b = blockIdx.x;
  const int t = threadIdx.x;
  const float* pm = blockIdx.y == 0 ? rpm : cpm;
  const float* ps = blockIdx.y == 0 ? rps : cps;
  float* fm = blockIdx.y == 0 ? rmax : cmax;
  float* fi = blockIdx.y == 0 ? rinv : cinv;
  float mj[4], sj[4];
  float m = -INFINITY;
#pragma unroll
  for (int j = 0; j < 4; ++j) {
    mj[j] = pm[((size_t)b * 4 + j) * NN + t];
    sj[j] = ps[((size_t)b * 4 + j) * NN + t];
    m = fmaxf(m, mj[j]);
  }
  float s = 0.f;
#pragma unroll
  for (int j = 0; j < 4; ++j)
    if (sj[j] > 0.f) s += sj[j] * __expf(mj[j] - m);
  fm[(size_t)b * NN + t] = m;
  fi[(size_t)b * NN + t] = 1.0f / s;
}

// --- Kernel 3: m_p : px_hat = softmax_h(e) @ hx, weights computed on the fly
__global__ __launch_bounds__(256) void gemm_wp(
    const float* __restrict__ E, const float* __restrict__ hxg,
    const float* __restrict__ pxg, const int* __restrict__ h_mask,
    const float* __restrict__ rmax, const float* __restrict__ rinv,
    float* __restrict__ outg) {
  __shared__ union {
    struct { char A[16384]; char B[16384]; } s;
    float ep[64][132];
  } u;
  const int b = blockIdx.z;
  const float* Eb = E + (size_t)b * NN * NN;
  const float* B = hxg + (size_t)b * NN * NN;
  const float* X = pxg + (size_t)b * NN * NN;
  const int* hm = h_mask + (size_t)b * NN;
  const float* rmx = rmax + (size_t)b * NN;
  const float* rin = rinv + (size_t)b * NN;
  float* out = outg + (size_t)b * NN * ROWC;
  const int row0 = blockIdx.y * 128, col0 = blockIdx.x * 128;
  const int t = threadIdx.x;
  const int l = t & 63, w = t >> 6;
  const int wr = w >> 1, wc = w & 1;

  float rmv[8];
#pragma unroll
  for (int i = 0; i < 8; ++i) rmv[i] = rmx[row0 + ((i * 256 + t) >> 4)];

  f32x4 acc[4][4];
#pragma unroll
  for (int i = 0; i < 4; ++i)
#pragma unroll
    for (int j = 0; j < 4; ++j)
#pragma unroll
      for (int r = 0; r < 4; ++r) acc[i][j][r] = 0.f;

  for (int k0 = 0; k0 < NN; k0 += 64) {
    // stage A: w = exp(e - rowmax), masked h -> 0, to bf16 frag order
#pragma unroll
    for (int i = 0; i < 8; ++i) {
      int idx = i * 256 + t;
      int r = idx >> 4, c4 = idx & 15, k = c4 << 2;
      float4 f = *(const float4*)&Eb[(size_t)(row0 + r) * NN + k0 + k];
      int4 m4 = *(const int4*)&hm[k0 + k];
      float w0 = m4.x ? 0.f : __expf(f.x - rmv[i]);
      float w1 = m4.y ? 0.f : __expf(f.y - rmv[i]);
      float w2 = m4.z ? 0.f : __expf(f.z - rmv[i]);
      float w3 = m4.w ? 0.f : __expf(f.w - rmv[i]);
      unsigned int p01 = bf16_rne(w0) | (bf16_rne(w1) << 16);
      unsigned int p23 = bf16_rne(w2) | (bf16_rne(w3) << 16);
      int khalf = k >> 5, k8 = (k >> 3) & 3, j = k & 7;
      int byte = frag_byte(r >> 4, (r & 15) + (k8 << 4), khalf) + (j << 1);
      *(uint2*)&u.s.A[byte] = make_uint2(p01, p23);
    }
    // stage B: hx fp32 [k][n] -> bf16, transposed into frag order (k-pairs)
#pragma unroll
    for (int i = 0; i < 4; ++i) {
      int idx = i * 256 + t;
      int kp = idx >> 5, nq = idx & 31;
      int k = kp << 1, n = nq << 2;
      const float* p0 = &B[(size_t)(k0 + k) * NN + col0 + n];
      float4 f0 = *(const float4*)p0;
      float4 f1 = *(const float4*)(p0 + NN);
      int khalf = k >> 5, k8 = (k >> 3) & 3, j = k & 7;
      float fa0[4] = {f0.x, f0.y, f0.z, f0.w};
      float fa1[4] = {f1.x, f1.y, f1.z, f1.w};
#pragma unroll
      for (int c = 0; c < 4; ++c) {
        unsigned int pk = bf16_rne(fa0[c]) | (bf16_rne(fa1[c]) << 16);
        int nn2 = n + c;
        int byte = frag_byte(nn2 >> 4, (nn2 & 15) + (k8 << 4), khalf) + (j << 1);
        *(unsigned int*)&u.s.B[byte] = pk;
      }
    }
    __syncthreads();
#pragma unroll
    for (int kh = 0; kh < 2; ++kh) {
      bf16x8 av[4], bv[4];
#pragma unroll
      for (int i = 0; i < 4; ++i) {
        av[i] = *(const bf16x8*)&u.s.A[frag_byte(wr * 4 + i, l, kh)];
        bv[i] = *(const bf16x8*)&u.s.B[frag_byte(wc * 4 + i, l, kh)];
      }
#pragma unroll
      for (int i = 0; i < 4; ++i)
#pragma unroll
        for (int j = 0; j < 4; ++j)
          acc[i][j] = __builtin_amdgcn_mfma_f32_16x16x32_bf16(av[i], bv[j], acc[i][j], 0, 0, 0);
    }
    __syncthreads();
  }

  const int g = l >> 4, li = l & 15;
#pragma unroll
  for (int pass = 0; pass < 2; ++pass) {
    if (wr == pass) {
#pragma unroll
      for (int i = 0; i < 4; ++i)
#pragma unroll
        for (int j = 0; j < 4; ++j)
#pragma unroll
          for (int r = 0; r < 4; ++r)
            u.ep[i * 16 + g * 4 + r][wc * 64 + j * 16 + li] = acc[i][j][r];
    }
    __syncthreads();
#pragma unroll
    for (int i = 0; i < 8; ++i) {
      int idx = i * 256 + t;
      int r = idx >> 5, c4 = idx & 31;
      int grow = row0 + pass * 64 + r;
      float ri = rin[grow];
      float4 ph = *(const float4*)&u.ep[r][c4 * 4];
      ph.x *= ri; ph.y *= ri; ph.z *= ri; ph.w *= ri;
      float4 xv = *(const float4*)&X[(size_t)grow * NN + col0 + c4 * 4];
      size_t base = (size_t)grow * ROWC + col0 + c4 * 4;
      *(float4*)&out[base] = xv;
      *(float4*)&out[base + 512] = ph;
      float4 df = {xv.x - ph.x, xv.y - ph.y, xv.z - ph.z, xv.w - ph.w};
      *(float4*)&out[base + 1024] = df;
      float4 pr = {xv.x * ph.x, xv.y * ph.y, xv.z * ph.z, xv.w * ph.w};
      *(float4*)&out[base + 1536] = pr;
    }
    __syncthreads();
  }
}

// --- Kernel 4: m_h : hx_hat = softmax_p(e)^T @ px, weights on the fly ------
__global__ __launch_bounds__(256) void gemm_wh(
    const float* __restrict__ E, const float* __restrict__ pxg,
    const float* __restrict__ hxg, const int* __restrict__ p_mask,
    const float* __restrict__ cmax, const float* __restrict__ cinv,
    float* __restrict__ outg) {
  __shared__ union {
    struct { char A[16384]; char B[16384]; } s;
    float ep[64][132];
  } u;
  const int b = blockIdx.z;
  const float* Eb = E + (size_t)b * NN * NN;
  const float* B = pxg + (size_t)b * NN * NN;
  const float* X = hxg + (size_t)b * NN * NN;
  const int* pmsk = p_mask + (size_t)b * NN;
  const float* cmx = cmax + (size_t)b * NN;
  const float* cin = cinv + (size_t)b * NN;
  float* out = outg + (size_t)b * NN * ROWC;
  const int row0 = blockIdx.y * 128, col0 = blockIdx.x * 128;  // rows = h
  const int t = threadIdx.x;
  const int l = t & 63, w = t >> 6;
  const int wr = w >> 1, wc = w & 1;

  float4 cmv[4];
#pragma unroll
  for (int i = 0; i < 4; ++i) {
    int idx = i * 256 + t;
    int n = (idx & 31) << 2;
    cmv[i] = *(const float4*)&cmx[row0 + n];
  }

  f32x4 acc[4][4];
#pragma unroll
  for (int i = 0; i < 4; ++i)
#pragma unroll
    for (int j = 0; j < 4; ++j)
#pragma unroll
      for (int r = 0; r < 4; ++r) acc[i][j][r] = 0.f;

  for (int k0 = 0; k0 < NN; k0 += 64) {
    // stage A: w[h][p] = exp(e[p][h] - colmax[h]), masked p -> 0 (k-pairs)
#pragma unroll
    for (int i = 0; i < 4; ++i) {
      int idx = i * 256 + t;
      int kp = idx >> 5, nq = idx & 31;
      int k = kp << 1, n = nq << 2;
      const float* p0 = &Eb[(size_t)(k0 + k) * NN + row0 + n];
      float4 f0 = *(const float4*)p0;
      float4 f1 = *(const float4*)(p0 + NN);
      int pm0 = pmsk[k0 + k], pm1 = pmsk[k0 + k + 1];
      float fa0[4] = {f0.x, f0.y, f0.z, f0.w};
      float fa1[4] = {f1.x, f1.y, f1.z, f1.w};
      float cma[4] = {cmv[i].x, cmv[i].y, cmv[i].z, cmv[i].w};
      int khalf = k >> 5, k8 = (k >> 3) & 3, j = k & 7;
#pragma unroll
      for (int c = 0; c < 4; ++c) {
        float w0 = pm0 ? 0.f : __expf(fa0[c] - cma[c]);
        float w1 = pm1 ? 0.f : __expf(fa1[c] - cma[c]);
        unsigned int pk = bf16_rne(w0) | (bf16_rne(w1) << 16);
        int nn2 = n + c;
        int byte = frag_byte(nn2 >> 4, (nn2 & 15) + (k8 << 4), khalf) + (j << 1);
        *(unsigned int*)&u.s.A[byte] = pk;
      }
    }
    // stage B: px fp32 [k][n] -> bf16 frag order (k-pairs)
#pragma unroll
    for (int i = 0; i < 4; ++i) {
      int idx = i * 256 + t;
      int kp = idx >> 5, nq = idx & 31;
      int k = kp << 1, n = nq << 2;
      const float* p0 = &B[(size_t)(k0 + k) * NN + col0 + n];
      float4 f0 = *(const float4*)p0;
      float4 f1 = *(const float4*)(p0 + NN);
      int khalf = k >> 5, k8 = (k >> 3) & 3, j = k & 7;
      float fa0[4] = {f0.x, f0.y, f0.z, f0.w};
      float fa1[4] = {f1.x, f1.y, f1.z, f1.w};
#pragma unroll
      for (int c = 0; c < 4; ++c) {
        unsigned int pk = bf16_rne(fa0[c]) | (bf16_rne(fa1[c]) << 16);
        int nn2 = n + c;
        int byte = frag_byte(nn2 >> 4, (nn2 & 15) + (k8 << 4), khalf) + (j << 1);
        *(unsigned int*)&u.s.B[byte] = pk;
      }
    }
    __syncthreads();
#pragma unroll
    for (int kh = 0; kh < 2; ++kh) {
      bf16x8 av[4], bv[4];
#pragma unroll
      for (int i = 0; i < 4; ++i) {
        av[i] = *(const bf16x8*)&u.s.A[frag_byte(wr * 4 + i, l, kh)];
        bv[i] = *(const bf16x8*)&u.s.B[frag_byte(wc * 4 + i, l, kh)];
      }
#pragma unroll
      for (int i = 0; i < 4; ++i)
#pragma unroll
        for (int j = 0; j < 4; ++j)
          acc[i][j] = __builtin_amdgcn_mfma_f32_16x16x32_bf16(av[i], bv[j], acc[i][j], 0, 0, 0);
    }
    __syncthreads();
  }

  const int g = l >> 4, li = l & 15;
#pragma unroll
  for (int pass = 0; pass < 2; ++pass) {
    if (wr == pass) {
#pragma unroll
      for (int i = 0; i < 4; ++i)
#pragma unroll
        for (int j = 0; j < 4; ++j)
#pragma unroll
          for (int r = 0; r < 4; ++r)
            u.ep[i * 16 + g * 4 + r][wc * 64 + j * 16 + li] = acc[i][j][r];
    }
    __syncthreads();
#pragma unroll
    for (int i = 0; i < 8; ++i) {
      int idx = i * 256 + t;
      int r = idx >> 5, c4 = idx & 31;
      int grow = row0 + pass * 64 + r;  // h
      float ci = cin[grow];
      float4 hh = *(const float4*)&u.ep[r][c4 * 4];
      hh.x *= ci; hh.y *= ci; hh.z *= ci; hh.w *= ci;
      float4 xv = *(const float4*)&X[(size_t)grow * NN + col0 + c4 * 4];
      size_t base = (size_t)grow * ROWC + col0 + c4 * 4;
      *(float4*)&out[base] = xv;
      *(float4*)&out[base + 512] = hh;
      float4 df = {xv.x - hh.x, xv.y - hh.y, xv.z - hh.z, xv.w - hh.w};
      *(float4*)&out[base + 1024] = df;
      float4 pr = {xv.x * hh.x, xv.y * hh.y, xv.z * hh.z, xv.w * hh.w};
      *(float4*)&out[base + 1536] = pr;
    }
    __syncthreads();
  }
}

extern "C" void kernel_launch(void* const* d_in, const int* in_sizes, int n_in,
                              void* d_out, int out_size, void* d_ws, size_t ws_size,
                              hipStream_t stream) {
  const float* px = (const float*)d_in[0];
  const float* hx = (const float*)d_in[1];
  const int* p_mask = (const int*)d_in[2];
  const int* h_mask = (const int*)d_in[3];
  float* out = (float*)d_out;

  float* E = (float*)d_ws;                         // 33.5 MB fp32
  float* rpm = E + (size_t)NB * NN * NN;           // [B][4][NN] partial row max
  float* rps = rpm + (size_t)NB * 4 * NN;
  float* cpm = rps + (size_t)NB * 4 * NN;
  float* cps = cpm + (size_t)NB * 4 * NN;
  float* rmaxv = cps + (size_t)NB * 4 * NN;        // [B][NN] finals
  float* rinvv = rmaxv + (size_t)NB * NN;
  float* cmaxv = rinvv + (size_t)NB * NN;
  float* cinvv = cmaxv + (size_t)NB * NN;

  dim3 gg(4, 4, NB);
  gemm_e_stats<<<gg, dim3(512), 0, stream>>>(px, hx, p_mask, h_mask, E, rpm, rps, cpm, cps);
  merge_stats<<<dim3(NB, 2), dim3(512), 0, stream>>>(rpm, rps, cpm, cps,
                                                     rmaxv, rinvv, cmaxv, cinvv);
  gemm_wp<<<gg, dim3(256), 0, stream>>>(E, hx, px, h_mask, rmaxv, rinvv, out);
  gemm_wh<<<gg, dim3(256), 0, stream>>>(E, px, hx, p_mask, cmaxv, cinvv,
                                        out + (size_t)NB * NN * ROWC);
}